// Round 3
// baseline (1306.559 us; speedup 1.0000x reference)
//
#include <hip/hip_runtime.h>

#define TPB 256
#define CAP 64   // slack-bucket capacity per node (avg in-degree 16, P(deg>64) ~ 1e-13)

// ---------------- out-degree histograms for both graphs (3.2M atomics) ----------------
__global__ void degout_kernel(const int* __restrict__ s1, const int* __restrict__ s2,
                              int* __restrict__ dout, int N, int E) {
    int i = blockIdx.x * TPB + threadIdx.x;
    int e = i * 4;
    if (e + 3 < E) {
        int4 a = ((const int4*)s1)[i];
        atomicAdd(&dout[a.x], 1); atomicAdd(&dout[a.y], 1);
        atomicAdd(&dout[a.z], 1); atomicAdd(&dout[a.w], 1);
        int4 b = ((const int4*)s2)[i];
        atomicAdd(&dout[N + b.x], 1); atomicAdd(&dout[N + b.y], 1);
        atomicAdd(&dout[N + b.z], 1); atomicAdd(&dout[N + b.w], 1);
    } else {
        for (; e < E; e++) {
            atomicAdd(&dout[s1[e]], 1);
            atomicAdd(&dout[N + s2[e]], 1);
        }
    }
}

__global__ void scale_kernel(const int* __restrict__ deg, float* __restrict__ scl, int n) {
    int i = blockIdx.x * TPB + threadIdx.x;
    if (i < n) {
        int d = deg[i];
        scl[i] = rsqrtf((float)(d > 1 ? d : 1));
    }
}

// ---------------- slack-bucket scatter: cursor atomic gives in-degree for free ------
__global__ void scatter_kernel(const int* __restrict__ src, const int* __restrict__ dst,
                               int* __restrict__ cnt, int* __restrict__ esrc, int E) {
    int i = blockIdx.x * TPB + threadIdx.x;
    int e = i * 4;
    if (e + 3 < E) {
        int4 s = ((const int4*)src)[i];
        int4 d = ((const int4*)dst)[i];
        int r;
        r = atomicAdd(&cnt[d.x], 1); if (r < CAP) esrc[d.x * CAP + r] = s.x;
        r = atomicAdd(&cnt[d.y], 1); if (r < CAP) esrc[d.y * CAP + r] = s.y;
        r = atomicAdd(&cnt[d.z], 1); if (r < CAP) esrc[d.z * CAP + r] = s.z;
        r = atomicAdd(&cnt[d.w], 1); if (r < CAP) esrc[d.w * CAP + r] = s.w;
    } else {
        for (; e < E; e++) {
            int dd = dst[e];
            int r = atomicAdd(&cnt[dd], 1);
            if (r < CAP) esrc[dd * CAP + r] = src[e];
        }
    }
}

// ---------------- GEMM 1: [N,128] @ [128,64], 64x64 tile, 4x4 per thread ----------------
__global__ void gemm1_kernel(const float* __restrict__ x, const float* __restrict__ W,
                             float* __restrict__ Y, int N) {
    __shared__ float xs[64 * 128];   // 32 KB
    __shared__ float ws[128 * 64];   // 32 KB
    int tid  = threadIdx.x;
    int row0 = blockIdx.x * 64;
    for (int i = tid; i < 2048; i += TPB)
        ((float4*)ws)[i] = ((const float4*)W)[i];
    for (int i = tid; i < 2048; i += TPB) {
        int r = row0 + (i >> 5);                 // 32 float4 per row
        ((float4*)xs)[i] = (r < N) ? ((const float4*)x)[(size_t)r * 32 + (i & 31)]
                                   : make_float4(0.f, 0.f, 0.f, 0.f);
    }
    __syncthreads();
    int tr = tid >> 4, tc = tid & 15;
    float acc[4][4] = {};
    for (int k4 = 0; k4 < 32; k4++) {
        float4 a[4], b[4];
        #pragma unroll
        for (int j = 0; j < 4; j++) a[j] = ((float4*)xs)[(tr * 4 + j) * 32 + k4];
        #pragma unroll
        for (int j = 0; j < 4; j++) b[j] = ((float4*)ws)[(k4 * 4 + j) * 16 + tc];
        #pragma unroll
        for (int i = 0; i < 4; i++) {
            float4 ai = a[i];
            acc[i][0] += ai.x * b[0].x + ai.y * b[1].x + ai.z * b[2].x + ai.w * b[3].x;
            acc[i][1] += ai.x * b[0].y + ai.y * b[1].y + ai.z * b[2].y + ai.w * b[3].y;
            acc[i][2] += ai.x * b[0].z + ai.y * b[1].z + ai.z * b[2].z + ai.w * b[3].z;
            acc[i][3] += ai.x * b[0].w + ai.y * b[1].w + ai.z * b[2].w + ai.w * b[3].w;
        }
    }
    #pragma unroll
    for (int i = 0; i < 4; i++) {
        int r = row0 + tr * 4 + i;
        if (r < N)
            ((float4*)Y)[(size_t)r * 16 + tc] =
                make_float4(acc[i][0], acc[i][1], acc[i][2], acc[i][3]);
    }
}

// ---------------- GEMM 2 (in place): H[:,0:32] = H[:,0:64] @ W2, 128x32 tile ------------
__global__ void gemm2_kernel(float* __restrict__ H, const float* __restrict__ W, int N) {
    __shared__ float xs[128 * 64];   // 32 KB
    __shared__ float ws[64 * 32];    // 8 KB
    int tid  = threadIdx.x;
    int row0 = blockIdx.x * 128;
    for (int i = tid; i < 512; i += TPB)
        ((float4*)ws)[i] = ((const float4*)W)[i];
    for (int i = tid; i < 2048; i += TPB) {
        int r = row0 + (i >> 4);                 // 16 float4 per row
        ((float4*)xs)[i] = (r < N) ? ((const float4*)H)[(size_t)r * 16 + (i & 15)]
                                   : make_float4(0.f, 0.f, 0.f, 0.f);
    }
    __syncthreads();
    int tr = tid >> 3, tc = tid & 7;
    float acc[4][4] = {};
    for (int k4 = 0; k4 < 16; k4++) {
        float4 a[4], b[4];
        #pragma unroll
        for (int j = 0; j < 4; j++) a[j] = ((float4*)xs)[(tr * 4 + j) * 16 + k4];
        #pragma unroll
        for (int j = 0; j < 4; j++) b[j] = ((float4*)ws)[(k4 * 4 + j) * 8 + tc];
        #pragma unroll
        for (int i = 0; i < 4; i++) {
            float4 ai = a[i];
            acc[i][0] += ai.x * b[0].x + ai.y * b[1].x + ai.z * b[2].x + ai.w * b[3].x;
            acc[i][1] += ai.x * b[0].y + ai.y * b[1].y + ai.z * b[2].y + ai.w * b[3].y;
            acc[i][2] += ai.x * b[0].z + ai.y * b[1].z + ai.z * b[2].z + ai.w * b[3].z;
            acc[i][3] += ai.x * b[0].w + ai.y * b[1].w + ai.z * b[2].w + ai.w * b[3].w;
        }
    }
    #pragma unroll
    for (int i = 0; i < 4; i++) {
        int r = row0 + tr * 4 + i;
        if (r < N)
            ((float4*)H)[(size_t)r * 16 + tc] =   // cols 0..31, row stride 64 floats
                make_float4(acc[i][0], acc[i][1], acc[i][2], acc[i][3]);
    }
}

// ---------------- layer-1 gather aggregate + fused s_in/bias/relu ----------------
// one wave per node, lane = feature (64)
__global__ void agg1_kernel(const int* __restrict__ esrc, const int* __restrict__ cnt,
                            const float* __restrict__ sout, const float* __restrict__ b1,
                            const float* __restrict__ Y1, float* __restrict__ H1, int N) {
    int node = blockIdx.x * 4 + (threadIdx.x >> 6);
    int f = threadIdx.x & 63;
    if (node >= N) return;
    int dn = cnt[node];
    float si = rsqrtf((float)(dn > 1 ? dn : 1));
    if (dn > CAP) dn = CAP;
    const int* es = esrc + (size_t)node * CAP;
    float acc = 0.f;
    int i = 0;
    for (; i + 4 <= dn; i += 4) {
        int s0 = es[i], s1 = es[i + 1], s2 = es[i + 2], s3 = es[i + 3];
        float w0 = sout[s0], w1 = sout[s1], w2 = sout[s2], w3 = sout[s3];
        acc += Y1[(size_t)s0 * 64 + f] * w0;
        acc += Y1[(size_t)s1 * 64 + f] * w1;
        acc += Y1[(size_t)s2 * 64 + f] * w2;
        acc += Y1[(size_t)s3 * 64 + f] * w3;
    }
    for (; i < dn; i++) {
        int s0 = es[i];
        acc += Y1[(size_t)s0 * 64 + f] * sout[s0];
    }
    float v = acc * si + b1[f];
    H1[(size_t)node * 64 + f] = v > 0.f ? v : 0.f;
}

// ---------------- layer-2 gather aggregate + fused epilogue (mean over graphs) ----------
// half-wave per node, lane = feature (32); H2 rows are stride-64
__global__ void agg2_kernel(const int* __restrict__ esrc, const int* __restrict__ cnt,
                            const float* __restrict__ sout, const float* __restrict__ b2,
                            const float* __restrict__ H2, float* __restrict__ out,
                            int N, int first) {
    int node = blockIdx.x * 8 + (threadIdx.x >> 5);
    int f = threadIdx.x & 31;
    if (node >= N) return;
    int dn = cnt[node];
    float si = rsqrtf((float)(dn > 1 ? dn : 1));
    if (dn > CAP) dn = CAP;
    const int* es = esrc + (size_t)node * CAP;
    float acc = 0.f;
    int i = 0;
    for (; i + 4 <= dn; i += 4) {
        int s0 = es[i], s1 = es[i + 1], s2 = es[i + 2], s3 = es[i + 3];
        float w0 = sout[s0], w1 = sout[s1], w2 = sout[s2], w3 = sout[s3];
        acc += H2[(size_t)s0 * 64 + f] * w0;
        acc += H2[(size_t)s1 * 64 + f] * w1;
        acc += H2[(size_t)s2 * 64 + f] * w2;
        acc += H2[(size_t)s3 * 64 + f] * w3;
    }
    for (; i < dn; i++) {
        int s0 = es[i];
        acc += H2[(size_t)s0 * 64 + f] * sout[s0];
    }
    float v = 0.5f * (acc * si + b2[f]);
    size_t o = (size_t)node * 32 + f;
    out[o] = first ? v : out[o] + v;
}

extern "C" void kernel_launch(void* const* d_in, const int* in_sizes, int n_in,
                              void* d_out, int out_size, void* d_ws, size_t ws_size,
                              hipStream_t stream) {
    const float* x    = (const float*)d_in[0];
    const int* srcs[2] = {(const int*)d_in[1], (const int*)d_in[3]};
    const int* dsts[2] = {(const int*)d_in[2], (const int*)d_in[4]};
    const float* W1   = (const float*)d_in[5];
    const float* b1   = (const float*)d_in[6];
    const float* W2   = (const float*)d_in[7];
    const float* b2   = (const float*)d_in[8];
    float* out        = (float*)d_out;

    const int N = in_sizes[0] / 128;   // 100000
    const int E = in_sizes[1];         // 1600000

    // workspace (floats): Y1[64N] | H1[64N] | ESRC[64N int] | DEGOUT[2N int] | SCLOUT[2N] | CNT[N int]
    float* ws     = (float*)d_ws;
    float* Y1     = ws;
    float* H1     = Y1 + (size_t)N * 64;
    int*   ESRC   = (int*)(H1 + (size_t)N * 64);
    int*   DEGOUT = ESRC + (size_t)N * CAP;
    float* SCLOUT = (float*)(DEGOUT + (size_t)2 * N);
    int*   CNT    = (int*)(SCLOUT + (size_t)2 * N);

    int eb4 = (E / 4 + TPB - 1) / TPB;

    hipMemsetAsync(DEGOUT, 0, sizeof(int) * (size_t)2 * N, stream);
    degout_kernel<<<eb4, TPB, 0, stream>>>(srcs[0], srcs[1], DEGOUT, N, E);
    scale_kernel<<<(2 * N + TPB - 1) / TPB, TPB, 0, stream>>>(DEGOUT, SCLOUT, 2 * N);

    gemm1_kernel<<<(N + 63) / 64, TPB, 0, stream>>>(x, W1, Y1, N);

    for (int g = 0; g < 2; g++) {
        const float* so = SCLOUT + (size_t)g * N;

        hipMemsetAsync(CNT, 0, sizeof(int) * (size_t)N, stream);
        scatter_kernel<<<eb4, TPB, 0, stream>>>(srcs[g], dsts[g], CNT, ESRC, E);

        agg1_kernel<<<(N + 3) / 4, TPB, 0, stream>>>(ESRC, CNT, so, b1, Y1, H1, N);
        gemm2_kernel<<<(N + 127) / 128, TPB, 0, stream>>>(H1, W2, N);
        agg2_kernel<<<(N + 7) / 8, TPB, 0, stream>>>(ESRC, CNT, so, b2, H1, out, N, g == 0);
    }
}

// Round 4
// 842.152 us; speedup vs baseline: 1.5515x; 1.5515x over previous
//
#include <hip/hip_runtime.h>

#define TPB 256

__device__ inline unsigned short f2bf(float f) {
    union { float f; unsigned int u; } v; v.f = f;
    unsigned int u = v.u + 0x7FFFu + ((v.u >> 16) & 1u);   // RTNE
    return (unsigned short)(u >> 16);
}
__device__ inline float bf2f(unsigned short h) {
    union { unsigned int u; float f; } v; v.u = ((unsigned int)h) << 16;
    return v.f;
}

// ---------------- all four degree histograms in one pass ----------------
// deg layout: [dout1 | din1 | dout2 | din2], each N
__global__ void deg_kernel(const int* __restrict__ s1, const int* __restrict__ d1,
                           const int* __restrict__ s2, const int* __restrict__ d2,
                           int* __restrict__ deg, int N, int E) {
    int i = blockIdx.x * TPB + threadIdx.x;
    int e = i * 4;
    int* dout1 = deg;
    int* din1  = deg + N;
    int* dout2 = deg + 2 * N;
    int* din2  = deg + 3 * N;
    if (e + 3 < E) {
        int4 a = ((const int4*)s1)[i];
        atomicAdd(&dout1[a.x], 1); atomicAdd(&dout1[a.y], 1);
        atomicAdd(&dout1[a.z], 1); atomicAdd(&dout1[a.w], 1);
        int4 b = ((const int4*)d1)[i];
        atomicAdd(&din1[b.x], 1); atomicAdd(&din1[b.y], 1);
        atomicAdd(&din1[b.z], 1); atomicAdd(&din1[b.w], 1);
        int4 c = ((const int4*)s2)[i];
        atomicAdd(&dout2[c.x], 1); atomicAdd(&dout2[c.y], 1);
        atomicAdd(&dout2[c.z], 1); atomicAdd(&dout2[c.w], 1);
        int4 d = ((const int4*)d2)[i];
        atomicAdd(&din2[d.x], 1); atomicAdd(&din2[d.y], 1);
        atomicAdd(&din2[d.z], 1); atomicAdd(&din2[d.w], 1);
    } else {
        for (; e < E; e++) {
            atomicAdd(&dout1[s1[e]], 1);
            atomicAdd(&din1[d1[e]], 1);
            atomicAdd(&dout2[s2[e]], 1);
            atomicAdd(&din2[d2[e]], 1);
        }
    }
}

// ---------------- scan (3-kernel exclusive prefix sum, verified round 2) ----------------
__global__ void scanA_kernel(const int* __restrict__ deg, int* __restrict__ bsum, int n) {
    __shared__ int lds[TPB];
    int t = threadIdx.x;
    int base = blockIdx.x * 1024;
    int s = 0;
    #pragma unroll
    for (int j = 0; j < 4; j++) {
        int idx = base + t * 4 + j;
        if (idx < n) s += deg[idx];
    }
    lds[t] = s;
    __syncthreads();
    for (int off = TPB / 2; off > 0; off >>= 1) {
        if (t < off) lds[t] += lds[t + off];
        __syncthreads();
    }
    if (t == 0) bsum[blockIdx.x] = lds[0];
}

__global__ void scanB_kernel(int* __restrict__ bsum, int nb) {
    if (threadIdx.x == 0 && blockIdx.x == 0) {
        int run = 0;
        for (int i = 0; i < nb; i++) { int v = bsum[i]; bsum[i] = run; run += v; }
    }
}

__global__ void scanC_kernel(const int* __restrict__ deg, const int* __restrict__ bsum,
                             int* __restrict__ rowptr, int n) {
    __shared__ int lds[TPB];
    int t = threadIdx.x;
    int base = blockIdx.x * 1024;
    int idx0 = base + t * 4;
    int d[4];
    #pragma unroll
    for (int j = 0; j < 4; j++) d[j] = (idx0 + j < n) ? deg[idx0 + j] : 0;
    int p1 = d[0], p2 = p1 + d[1], p3 = p2 + d[2], ts = p3 + d[3];
    lds[t] = ts;
    __syncthreads();
    for (int off = 1; off < TPB; off <<= 1) {
        int v = (t >= off) ? lds[t - off] : 0;
        __syncthreads();
        lds[t] += v;
        __syncthreads();
    }
    int excl = lds[t] - ts + bsum[blockIdx.x];
    if (idx0 < n)     rowptr[idx0]     = excl;
    if (idx0 + 1 < n) rowptr[idx0 + 1] = excl + p1;
    if (idx0 + 2 < n) rowptr[idx0 + 2] = excl + p2;
    if (idx0 + 3 < n) rowptr[idx0 + 3] = excl + p3;
}

// ---------------- scatter: cnt pre-initialized to rowptr (2 line-touches/edge) ---------
__global__ void scatter_kernel(const int* __restrict__ src, const int* __restrict__ dst,
                               int* __restrict__ cnt, int* __restrict__ esrc, int E) {
    int i = blockIdx.x * TPB + threadIdx.x;
    int e = i * 4;
    if (e + 3 < E) {
        int4 s = ((const int4*)src)[i];
        int4 d = ((const int4*)dst)[i];
        esrc[atomicAdd(&cnt[d.x], 1)] = s.x;
        esrc[atomicAdd(&cnt[d.y], 1)] = s.y;
        esrc[atomicAdd(&cnt[d.z], 1)] = s.z;
        esrc[atomicAdd(&cnt[d.w], 1)] = s.w;
    } else {
        for (; e < E; e++) esrc[atomicAdd(&cnt[dst[e]], 1)] = src[e];
    }
}

// ---------------- GEMM 1: [N,128] @ [128,64]; epilogue -> two sout-scaled bf16 copies ---
__global__ void gemm1_kernel(const float* __restrict__ x, const float* __restrict__ W,
                             const int* __restrict__ dout1, const int* __restrict__ dout2,
                             unsigned short* __restrict__ Y0, unsigned short* __restrict__ Y1,
                             int N) {
    __shared__ float xs[64 * 128];   // 32 KB
    __shared__ float ws[128 * 64];   // 32 KB
    int tid  = threadIdx.x;
    int row0 = blockIdx.x * 64;
    for (int i = tid; i < 2048; i += TPB)
        ((float4*)ws)[i] = ((const float4*)W)[i];
    for (int i = tid; i < 2048; i += TPB) {
        int r = row0 + (i >> 5);
        ((float4*)xs)[i] = (r < N) ? ((const float4*)x)[(size_t)r * 32 + (i & 31)]
                                   : make_float4(0.f, 0.f, 0.f, 0.f);
    }
    __syncthreads();
    int tr = tid >> 4, tc = tid & 15;
    float acc[4][4] = {};
    for (int k4 = 0; k4 < 32; k4++) {
        float4 a[4], b[4];
        #pragma unroll
        for (int j = 0; j < 4; j++) a[j] = ((float4*)xs)[(tr * 4 + j) * 32 + k4];
        #pragma unroll
        for (int j = 0; j < 4; j++) b[j] = ((float4*)ws)[(k4 * 4 + j) * 16 + tc];
        #pragma unroll
        for (int i = 0; i < 4; i++) {
            float4 ai = a[i];
            acc[i][0] += ai.x * b[0].x + ai.y * b[1].x + ai.z * b[2].x + ai.w * b[3].x;
            acc[i][1] += ai.x * b[0].y + ai.y * b[1].y + ai.z * b[2].y + ai.w * b[3].y;
            acc[i][2] += ai.x * b[0].z + ai.y * b[1].z + ai.z * b[2].z + ai.w * b[3].z;
            acc[i][3] += ai.x * b[0].w + ai.y * b[1].w + ai.z * b[2].w + ai.w * b[3].w;
        }
    }
    #pragma unroll
    for (int i = 0; i < 4; i++) {
        int r = row0 + tr * 4 + i;
        if (r < N) {
            int g0 = dout1[r], g1 = dout2[r];
            float s0 = rsqrtf((float)(g0 > 1 ? g0 : 1));
            float s1 = rsqrtf((float)(g1 > 1 ? g1 : 1));
            size_t o = (size_t)r * 64 + tc * 4;
            ushort4 p0 = make_ushort4(f2bf(acc[i][0] * s0), f2bf(acc[i][1] * s0),
                                      f2bf(acc[i][2] * s0), f2bf(acc[i][3] * s0));
            ushort4 p1 = make_ushort4(f2bf(acc[i][0] * s1), f2bf(acc[i][1] * s1),
                                      f2bf(acc[i][2] * s1), f2bf(acc[i][3] * s1));
            *(ushort4*)(Y0 + o) = p0;
            *(ushort4*)(Y1 + o) = p1;
        }
    }
}

// ---------------- GEMM 2: H1[N,64] @ W2[64,32] -> sout-scaled bf16 H2[N,32] -------------
__global__ void gemm2_kernel(const float* __restrict__ H, const float* __restrict__ W,
                             const int* __restrict__ dout, unsigned short* __restrict__ H2,
                             int N) {
    __shared__ float xs[32 * 64];    // 8 KB
    __shared__ float ws[64 * 32];    // 8 KB
    int tid  = threadIdx.x;
    int row0 = blockIdx.x * 32;
    for (int i = tid; i < 512; i += TPB)
        ((float4*)ws)[i] = ((const float4*)W)[i];
    for (int i = tid; i < 512; i += TPB) {
        int r = row0 + (i >> 4);
        ((float4*)xs)[i] = (r < N) ? ((const float4*)H)[(size_t)r * 16 + (i & 15)]
                                   : make_float4(0.f, 0.f, 0.f, 0.f);
    }
    __syncthreads();
    int c  = tid & 31;
    int r0 = tid >> 5;
    for (int rr = 0; rr < 4; rr++) {
        int r = r0 + rr * 8;
        float acc = 0.f;
        #pragma unroll
        for (int k = 0; k < 64; k++) acc += xs[r * 64 + k] * ws[k * 32 + c];
        int grow = row0 + r;
        if (grow < N) {
            int g = dout[grow];
            float so = rsqrtf((float)(g > 1 ? g : 1));
            H2[(size_t)grow * 32 + c] = f2bf(acc * so);
        }
    }
}

// ---------------- layer-1 gather (bf16 rows, pre-scaled) + bias/relu ----------------
__global__ void agg1_kernel(const int* __restrict__ esrc, const int* __restrict__ rowptr,
                            const int* __restrict__ din, const unsigned short* __restrict__ Yg,
                            const float* __restrict__ b1, float* __restrict__ H1, int N) {
    int node = blockIdx.x * 4 + (threadIdx.x >> 6);
    int f = threadIdx.x & 63;
    if (node >= N) return;
    int dn = din[node];
    float si = rsqrtf((float)(dn > 1 ? dn : 1));
    const int* es = esrc + rowptr[node];
    float acc = 0.f;
    int i = 0;
    for (; i + 4 <= dn; i += 4) {
        int s0 = es[i], s1 = es[i + 1], s2 = es[i + 2], s3 = es[i + 3];
        acc += bf2f(Yg[(size_t)s0 * 64 + f]);
        acc += bf2f(Yg[(size_t)s1 * 64 + f]);
        acc += bf2f(Yg[(size_t)s2 * 64 + f]);
        acc += bf2f(Yg[(size_t)s3 * 64 + f]);
    }
    for (; i < dn; i++) acc += bf2f(Yg[(size_t)es[i] * 64 + f]);
    float v = acc * si + b1[f];
    H1[(size_t)node * 64 + f] = v > 0.f ? v : 0.f;
}

// ---------------- layer-2 gather (bf16 rows, pre-scaled) + mean epilogue ----------------
__global__ void agg2_kernel(const int* __restrict__ esrc, const int* __restrict__ rowptr,
                            const int* __restrict__ din, const unsigned short* __restrict__ H2,
                            const float* __restrict__ b2, float* __restrict__ out,
                            int N, int first) {
    int node = blockIdx.x * 8 + (threadIdx.x >> 5);
    int f = threadIdx.x & 31;
    if (node >= N) return;
    int dn = din[node];
    float si = rsqrtf((float)(dn > 1 ? dn : 1));
    const int* es = esrc + rowptr[node];
    float acc = 0.f;
    int i = 0;
    for (; i + 4 <= dn; i += 4) {
        int s0 = es[i], s1 = es[i + 1], s2 = es[i + 2], s3 = es[i + 3];
        acc += bf2f(H2[(size_t)s0 * 32 + f]);
        acc += bf2f(H2[(size_t)s1 * 32 + f]);
        acc += bf2f(H2[(size_t)s2 * 32 + f]);
        acc += bf2f(H2[(size_t)s3 * 32 + f]);
    }
    for (; i < dn; i++) acc += bf2f(H2[(size_t)es[i] * 32 + f]);
    float v = 0.5f * (acc * si + b2[f]);
    size_t o = (size_t)node * 32 + f;
    out[o] = first ? v : out[o] + v;
}

extern "C" void kernel_launch(void* const* d_in, const int* in_sizes, int n_in,
                              void* d_out, int out_size, void* d_ws, size_t ws_size,
                              hipStream_t stream) {
    const float* x    = (const float*)d_in[0];
    const int* srcs[2] = {(const int*)d_in[1], (const int*)d_in[3]};
    const int* dsts[2] = {(const int*)d_in[2], (const int*)d_in[4]};
    const float* W1   = (const float*)d_in[5];
    const float* b1   = (const float*)d_in[6];
    const float* W2   = (const float*)d_in[7];
    const float* b2   = (const float*)d_in[8];
    float* out        = (float*)d_out;

    const int N = in_sizes[0] / 128;   // 100000
    const int E = in_sizes[1];         // 1600000
    const int NB1024 = (N + 1023) / 1024;

    // byte layout: Y1G0(bf16 64N) | Y1G1(bf16 64N) | H1(f32 64N) | H2(bf16 32N)
    //              | DEG(4N int) | ROWPTR(N) | CNT(N) | BSUM(128) | ESRC(E)   ~= 66.4 MB
    unsigned short* Y1G0 = (unsigned short*)d_ws;
    unsigned short* Y1G1 = Y1G0 + (size_t)64 * N;
    float* H1            = (float*)(Y1G1 + (size_t)64 * N);
    unsigned short* H2   = (unsigned short*)(H1 + (size_t)64 * N);
    int* DEG             = (int*)(H2 + (size_t)32 * N);
    int* ROWPTR          = DEG + (size_t)4 * N;
    int* CNT             = ROWPTR + N;
    int* BSUM            = CNT + N;
    int* ESRC            = BSUM + 128;

    int eb4 = (E / 4 + TPB - 1) / TPB;

    hipMemsetAsync(DEG, 0, sizeof(int) * (size_t)4 * N, stream);
    deg_kernel<<<eb4, TPB, 0, stream>>>(srcs[0], dsts[0], srcs[1], dsts[1], DEG, N, E);

    // gemm1 + dual pre-scaled bf16 epilogue (needs dout1/dout2)
    gemm1_kernel<<<(N + 63) / 64, TPB, 0, stream>>>(x, W1, DEG, DEG + 2 * N, Y1G0, Y1G1, N);

    for (int g = 0; g < 2; g++) {
        const int* din  = DEG + (size_t)(2 * g + 1) * N;
        const int* dogc = DEG + (size_t)(2 * g) * N;
        const unsigned short* Yg = g == 0 ? Y1G0 : Y1G1;

        scanA_kernel<<<NB1024, TPB, 0, stream>>>(din, BSUM, N);
        scanB_kernel<<<1, TPB, 0, stream>>>(BSUM, NB1024);
        scanC_kernel<<<NB1024, TPB, 0, stream>>>(din, BSUM, ROWPTR, N);
        hipMemcpyAsync(CNT, ROWPTR, sizeof(int) * (size_t)N, hipMemcpyDeviceToDevice, stream);
        scatter_kernel<<<eb4, TPB, 0, stream>>>(srcs[g], dsts[g], CNT, ESRC, E);

        agg1_kernel<<<(N + 3) / 4, TPB, 0, stream>>>(ESRC, ROWPTR, din, Yg, b1, H1, N);
        gemm2_kernel<<<(N + 31) / 32, TPB, 0, stream>>>(H1, W2, dogc, H2, N);
        agg2_kernel<<<(N + 7) / 8, TPB, 0, stream>>>(ESRC, ROWPTR, din, H2, b2, out, N, g == 0);
    }
}

// Round 5
// 840.599 us; speedup vs baseline: 1.5543x; 1.0018x over previous
//
#include <hip/hip_runtime.h>

#define TPB 256
#define NXCD 8

__device__ inline unsigned short f2bf(float f) {
    union { float f; unsigned int u; } v; v.f = f;
    unsigned int u = v.u + 0x7FFFu + ((v.u >> 16) & 1u);   // RTNE
    return (unsigned short)(u >> 16);
}
__device__ inline float bf2f(unsigned short h) {
    union { unsigned int u; float f; } v; v.u = ((unsigned int)h) << 16;
    return v.f;
}

__device__ inline unsigned xcd_id() {
    unsigned x;
    asm volatile("s_getreg_b32 %0, hwreg(HW_REG_XCC_ID)" : "=s"(x));
    return x & (NXCD - 1);
}

// XCD-local (L2-resident) atomic increment: no cross-XCD fabric RMW
__device__ inline void xadd(int* p) {
    __hip_atomic_fetch_add(p, 1, __ATOMIC_RELAXED, __HIP_MEMORY_SCOPE_WORKGROUP);
}

// ---------------- degree histograms, privatized per XCD ----------------
// degp layout: [xcd][dout1 | din1 | dout2 | din2], each section N
__global__ void deg_kernel(const int* __restrict__ s1, const int* __restrict__ d1,
                           const int* __restrict__ s2, const int* __restrict__ d2,
                           int* __restrict__ degp, int N, int E) {
    int* base  = degp + (size_t)xcd_id() * 4 * N;
    int* dout1 = base;
    int* din1  = base + N;
    int* dout2 = base + 2 * N;
    int* din2  = base + 3 * N;
    int i = blockIdx.x * TPB + threadIdx.x;
    int e = i * 4;
    if (e + 3 < E) {
        int4 a = ((const int4*)s1)[i];
        xadd(&dout1[a.x]); xadd(&dout1[a.y]); xadd(&dout1[a.z]); xadd(&dout1[a.w]);
        int4 b = ((const int4*)d1)[i];
        xadd(&din1[b.x]);  xadd(&din1[b.y]);  xadd(&din1[b.z]);  xadd(&din1[b.w]);
        int4 c = ((const int4*)s2)[i];
        xadd(&dout2[c.x]); xadd(&dout2[c.y]); xadd(&dout2[c.z]); xadd(&dout2[c.w]);
        int4 d = ((const int4*)d2)[i];
        xadd(&din2[d.x]);  xadd(&din2[d.y]);  xadd(&din2[d.z]);  xadd(&din2[d.w]);
    } else {
        for (; e < E; e++) {
            xadd(&dout1[s1[e]]);
            xadd(&din1[d1[e]]);
            xadd(&dout2[s2[e]]);
            xadd(&din2[d2[e]]);
        }
    }
}

// merge the 8 per-XCD copies (kernel boundary made them coherent)
__global__ void degmerge_kernel(const int* __restrict__ degp, int* __restrict__ deg,
                                int total /* 4N */) {
    int i = blockIdx.x * TPB + threadIdx.x;
    if (i < total) {
        int s = 0;
        #pragma unroll
        for (int x = 0; x < NXCD; x++) s += degp[(size_t)x * total + i];
        deg[i] = s;
    }
}

// ---------------- scan (3-kernel exclusive prefix sum) ----------------
__global__ void scanA_kernel(const int* __restrict__ deg, int* __restrict__ bsum, int n) {
    __shared__ int lds[TPB];
    int t = threadIdx.x;
    int base = blockIdx.x * 1024;
    int s = 0;
    #pragma unroll
    for (int j = 0; j < 4; j++) {
        int idx = base + t * 4 + j;
        if (idx < n) s += deg[idx];
    }
    lds[t] = s;
    __syncthreads();
    for (int off = TPB / 2; off > 0; off >>= 1) {
        if (t < off) lds[t] += lds[t + off];
        __syncthreads();
    }
    if (t == 0) bsum[blockIdx.x] = lds[0];
}

__global__ void scanB_kernel(int* __restrict__ bsum, int nb) {
    if (threadIdx.x == 0 && blockIdx.x == 0) {
        int run = 0;
        for (int i = 0; i < nb; i++) { int v = bsum[i]; bsum[i] = run; run += v; }
    }
}

__global__ void scanC_kernel(const int* __restrict__ deg, const int* __restrict__ bsum,
                             int* __restrict__ rowptr, int n) {
    __shared__ int lds[TPB];
    int t = threadIdx.x;
    int base = blockIdx.x * 1024;
    int idx0 = base + t * 4;
    int d[4];
    #pragma unroll
    for (int j = 0; j < 4; j++) d[j] = (idx0 + j < n) ? deg[idx0 + j] : 0;
    int p1 = d[0], p2 = p1 + d[1], p3 = p2 + d[2], ts = p3 + d[3];
    lds[t] = ts;
    __syncthreads();
    for (int off = 1; off < TPB; off <<= 1) {
        int v = (t >= off) ? lds[t - off] : 0;
        __syncthreads();
        lds[t] += v;
        __syncthreads();
    }
    int excl = lds[t] - ts + bsum[blockIdx.x];
    if (idx0 < n)     rowptr[idx0]     = excl;
    if (idx0 + 1 < n) rowptr[idx0 + 1] = excl + p1;
    if (idx0 + 2 < n) rowptr[idx0 + 2] = excl + p2;
    if (idx0 + 3 < n) rowptr[idx0 + 3] = excl + p3;
}

// ---------------- scatter: cnt pre-initialized to rowptr ----------------
__global__ void scatter_kernel(const int* __restrict__ src, const int* __restrict__ dst,
                               int* __restrict__ cnt, int* __restrict__ esrc, int E) {
    int i = blockIdx.x * TPB + threadIdx.x;
    int e = i * 4;
    if (e + 3 < E) {
        int4 s = ((const int4*)src)[i];
        int4 d = ((const int4*)dst)[i];
        esrc[atomicAdd(&cnt[d.x], 1)] = s.x;
        esrc[atomicAdd(&cnt[d.y], 1)] = s.y;
        esrc[atomicAdd(&cnt[d.z], 1)] = s.z;
        esrc[atomicAdd(&cnt[d.w], 1)] = s.w;
    } else {
        for (; e < E; e++) esrc[atomicAdd(&cnt[dst[e]], 1)] = src[e];
    }
}

// ---------------- GEMM 1: [N,128] @ [128,64]; epilogue -> two sout-scaled bf16 copies ---
__global__ void gemm1_kernel(const float* __restrict__ x, const float* __restrict__ W,
                             const int* __restrict__ dout1, const int* __restrict__ dout2,
                             unsigned short* __restrict__ Y0, unsigned short* __restrict__ Y1,
                             int N) {
    __shared__ float xs[64 * 128];   // 32 KB
    __shared__ float ws[128 * 64];   // 32 KB
    int tid  = threadIdx.x;
    int row0 = blockIdx.x * 64;
    for (int i = tid; i < 2048; i += TPB)
        ((float4*)ws)[i] = ((const float4*)W)[i];
    for (int i = tid; i < 2048; i += TPB) {
        int r = row0 + (i >> 5);
        ((float4*)xs)[i] = (r < N) ? ((const float4*)x)[(size_t)r * 32 + (i & 31)]
                                   : make_float4(0.f, 0.f, 0.f, 0.f);
    }
    __syncthreads();
    int tr = tid >> 4, tc = tid & 15;
    float acc[4][4] = {};
    for (int k4 = 0; k4 < 32; k4++) {
        float4 a[4], b[4];
        #pragma unroll
        for (int j = 0; j < 4; j++) a[j] = ((float4*)xs)[(tr * 4 + j) * 32 + k4];
        #pragma unroll
        for (int j = 0; j < 4; j++) b[j] = ((float4*)ws)[(k4 * 4 + j) * 16 + tc];
        #pragma unroll
        for (int i = 0; i < 4; i++) {
            float4 ai = a[i];
            acc[i][0] += ai.x * b[0].x + ai.y * b[1].x + ai.z * b[2].x + ai.w * b[3].x;
            acc[i][1] += ai.x * b[0].y + ai.y * b[1].y + ai.z * b[2].y + ai.w * b[3].y;
            acc[i][2] += ai.x * b[0].z + ai.y * b[1].z + ai.z * b[2].z + ai.w * b[3].z;
            acc[i][3] += ai.x * b[0].w + ai.y * b[1].w + ai.z * b[2].w + ai.w * b[3].w;
        }
    }
    #pragma unroll
    for (int i = 0; i < 4; i++) {
        int r = row0 + tr * 4 + i;
        if (r < N) {
            int g0 = dout1[r], g1 = dout2[r];
            float s0 = rsqrtf((float)(g0 > 1 ? g0 : 1));
            float s1 = rsqrtf((float)(g1 > 1 ? g1 : 1));
            size_t o = (size_t)r * 64 + tc * 4;
            ushort4 p0 = make_ushort4(f2bf(acc[i][0] * s0), f2bf(acc[i][1] * s0),
                                      f2bf(acc[i][2] * s0), f2bf(acc[i][3] * s0));
            ushort4 p1 = make_ushort4(f2bf(acc[i][0] * s1), f2bf(acc[i][1] * s1),
                                      f2bf(acc[i][2] * s1), f2bf(acc[i][3] * s1));
            *(ushort4*)(Y0 + o) = p0;
            *(ushort4*)(Y1 + o) = p1;
        }
    }
}

// ---------------- GEMM 2: H1[N,64] @ W2[64,32] -> sout-scaled bf16 H2[N,32] -------------
__global__ void gemm2_kernel(const float* __restrict__ H, const float* __restrict__ W,
                             const int* __restrict__ dout, unsigned short* __restrict__ H2,
                             int N) {
    __shared__ float xs[32 * 64];    // 8 KB
    __shared__ float ws[64 * 32];    // 8 KB
    int tid  = threadIdx.x;
    int row0 = blockIdx.x * 32;
    for (int i = tid; i < 512; i += TPB)
        ((float4*)ws)[i] = ((const float4*)W)[i];
    for (int i = tid; i < 512; i += TPB) {
        int r = row0 + (i >> 4);
        ((float4*)xs)[i] = (r < N) ? ((const float4*)H)[(size_t)r * 16 + (i & 15)]
                                   : make_float4(0.f, 0.f, 0.f, 0.f);
    }
    __syncthreads();
    int c  = tid & 31;
    int r0 = tid >> 5;
    for (int rr = 0; rr < 4; rr++) {
        int r = r0 + rr * 8;
        float acc = 0.f;
        #pragma unroll
        for (int k = 0; k < 64; k++) acc += xs[r * 64 + k] * ws[k * 32 + c];
        int grow = row0 + r;
        if (grow < N) {
            int g = dout[grow];
            float so = rsqrtf((float)(g > 1 ? g : 1));
            H2[(size_t)grow * 32 + c] = f2bf(acc * so);
        }
    }
}

// ---------------- layer-1 gather (bf16 rows, pre-scaled) + bias/relu ----------------
__global__ void agg1_kernel(const int* __restrict__ esrc, const int* __restrict__ rowptr,
                            const int* __restrict__ din, const unsigned short* __restrict__ Yg,
                            const float* __restrict__ b1, float* __restrict__ H1, int N) {
    int node = blockIdx.x * 4 + (threadIdx.x >> 6);
    int f = threadIdx.x & 63;
    if (node >= N) return;
    int dn = din[node];
    float si = rsqrtf((float)(dn > 1 ? dn : 1));
    const int* es = esrc + rowptr[node];
    float acc = 0.f;
    int i = 0;
    for (; i + 4 <= dn; i += 4) {
        int s0 = es[i], s1 = es[i + 1], s2 = es[i + 2], s3 = es[i + 3];
        acc += bf2f(Yg[(size_t)s0 * 64 + f]);
        acc += bf2f(Yg[(size_t)s1 * 64 + f]);
        acc += bf2f(Yg[(size_t)s2 * 64 + f]);
        acc += bf2f(Yg[(size_t)s3 * 64 + f]);
    }
    for (; i < dn; i++) acc += bf2f(Yg[(size_t)es[i] * 64 + f]);
    float v = acc * si + b1[f];
    H1[(size_t)node * 64 + f] = v > 0.f ? v : 0.f;
}

// ---------------- layer-2 gather (bf16 rows, pre-scaled) + mean epilogue ----------------
__global__ void agg2_kernel(const int* __restrict__ esrc, const int* __restrict__ rowptr,
                            const int* __restrict__ din, const unsigned short* __restrict__ H2,
                            const float* __restrict__ b2, float* __restrict__ out,
                            int N, int first) {
    int node = blockIdx.x * 8 + (threadIdx.x >> 5);
    int f = threadIdx.x & 31;
    if (node >= N) return;
    int dn = din[node];
    float si = rsqrtf((float)(dn > 1 ? dn : 1));
    const int* es = esrc + rowptr[node];
    float acc = 0.f;
    int i = 0;
    for (; i + 4 <= dn; i += 4) {
        int s0 = es[i], s1 = es[i + 1], s2 = es[i + 2], s3 = es[i + 3];
        acc += bf2f(H2[(size_t)s0 * 32 + f]);
        acc += bf2f(H2[(size_t)s1 * 32 + f]);
        acc += bf2f(H2[(size_t)s2 * 32 + f]);
        acc += bf2f(H2[(size_t)s3 * 32 + f]);
    }
    for (; i < dn; i++) acc += bf2f(H2[(size_t)es[i] * 32 + f]);
    float v = 0.5f * (acc * si + b2[f]);
    size_t o = (size_t)node * 32 + f;
    out[o] = first ? v : out[o] + v;
}

extern "C" void kernel_launch(void* const* d_in, const int* in_sizes, int n_in,
                              void* d_out, int out_size, void* d_ws, size_t ws_size,
                              hipStream_t stream) {
    const float* x    = (const float*)d_in[0];
    const int* srcs[2] = {(const int*)d_in[1], (const int*)d_in[3]};
    const int* dsts[2] = {(const int*)d_in[2], (const int*)d_in[4]};
    const float* W1   = (const float*)d_in[5];
    const float* b1   = (const float*)d_in[6];
    const float* W2   = (const float*)d_in[7];
    const float* b2   = (const float*)d_in[8];
    float* out        = (float*)d_out;

    const int N = in_sizes[0] / 128;   // 100000
    const int E = in_sizes[1];         // 1600000
    const int NB1024 = (N + 1023) / 1024;

    // byte layout: Y1G0(bf16 64N)=12.8M | Y1G1=12.8M | H1(f32 64N)=25.6M | H2(bf16 32N)=6.4M
    //   | DEGP(int 8*4N)=12.8M | DEG(4N)=1.6M | ROWPTR(N) | CNT(N) | BSUM(128) | ESRC(E)=6.4M
    //   total ~ 79.2 MB
    unsigned short* Y1G0 = (unsigned short*)d_ws;
    unsigned short* Y1G1 = Y1G0 + (size_t)64 * N;
    float* H1            = (float*)(Y1G1 + (size_t)64 * N);
    unsigned short* H2   = (unsigned short*)(H1 + (size_t)64 * N);
    int* DEGP            = (int*)(H2 + (size_t)32 * N);
    int* DEG             = DEGP + (size_t)NXCD * 4 * N;
    int* ROWPTR          = DEG + (size_t)4 * N;
    int* CNT             = ROWPTR + N;
    int* BSUM            = CNT + N;
    int* ESRC            = BSUM + 128;

    int eb4 = (E / 4 + TPB - 1) / TPB;

    hipMemsetAsync(DEGP, 0, sizeof(int) * (size_t)NXCD * 4 * N, stream);
    deg_kernel<<<eb4, TPB, 0, stream>>>(srcs[0], dsts[0], srcs[1], dsts[1], DEGP, N, E);
    degmerge_kernel<<<(4 * N + TPB - 1) / TPB, TPB, 0, stream>>>(DEGP, DEG, 4 * N);

    gemm1_kernel<<<(N + 63) / 64, TPB, 0, stream>>>(x, W1, DEG, DEG + 2 * N, Y1G0, Y1G1, N);

    for (int g = 0; g < 2; g++) {
        const int* din  = DEG + (size_t)(2 * g + 1) * N;
        const int* dogc = DEG + (size_t)(2 * g) * N;
        const unsigned short* Yg = g == 0 ? Y1G0 : Y1G1;

        scanA_kernel<<<NB1024, TPB, 0, stream>>>(din, BSUM, N);
        scanB_kernel<<<1, TPB, 0, stream>>>(BSUM, NB1024);
        scanC_kernel<<<NB1024, TPB, 0, stream>>>(din, BSUM, ROWPTR, N);
        hipMemcpyAsync(CNT, ROWPTR, sizeof(int) * (size_t)N, hipMemcpyDeviceToDevice, stream);
        scatter_kernel<<<eb4, TPB, 0, stream>>>(srcs[g], dsts[g], CNT, ESRC, E);

        agg1_kernel<<<(N + 3) / 4, TPB, 0, stream>>>(ESRC, ROWPTR, din, Yg, b1, H1, N);
        gemm2_kernel<<<(N + 31) / 32, TPB, 0, stream>>>(H1, W2, dogc, H2, N);
        agg2_kernel<<<(N + 7) / 8, TPB, 0, stream>>>(ESRC, ROWPTR, din, H2, b2, out, N, g == 0);
    }
}

// Round 6
// 609.233 us; speedup vs baseline: 2.1446x; 1.3798x over previous
//
#include <hip/hip_runtime.h>

#define TPB 256
#define CAP 48          // slack-bucket capacity (deg_in ~ Poisson(16); P(>48) ~ 3e-10/node)
#define CHUNK 8192      // nodes per LDS histogram chunk (32 KB)
#define GPART 32        // edge-array partitions per chunk

__device__ inline unsigned short f2bf(float f) {
    union { float f; unsigned int u; } v; v.f = f;
    unsigned int u = v.u + 0x7FFFu + ((v.u >> 16) & 1u);   // RTNE
    return (unsigned short)(u >> 16);
}
__device__ inline float bf2f(unsigned short h) {
    union { unsigned int u; float f; } v; v.u = ((unsigned int)h) << 16;
    return v.f;
}

// ---------------- out-degree histograms via LDS chunking (NO global atomics) -----------
// grid = 2 * nchunk * GPART; block b -> (which array, chunk, partition)
// partial layout: part[b][CHUNK]
__global__ void hist_kernel(const int* __restrict__ s1, const int* __restrict__ s2,
                            int* __restrict__ part, int N, int E, int nchunk) {
    __shared__ int h[CHUNK];
    int b     = blockIdx.x;
    int which = b / (nchunk * GPART);
    int rem   = b % (nchunk * GPART);
    int chunk = rem / GPART;
    int p     = rem % GPART;
    const int* src = which ? s2 : s1;

    for (int i = threadIdx.x; i < CHUNK; i += TPB) h[i] = 0;
    __syncthreads();

    int lo  = chunk * CHUNK;
    int per = ((E + GPART - 1) / GPART + 3) & ~3;   // multiple of 4 for int4 alignment
    int e0  = p * per;
    int e1  = e0 + per; if (e1 > E) e1 = E;
    if (e0 < e1) {
        int nvec = (e1 - e0) >> 2;
        const int4* vsrc = (const int4*)(src + e0);
        for (int i = threadIdx.x; i < nvec; i += TPB) {
            int4 v = vsrc[i];
            unsigned d;
            d = (unsigned)(v.x - lo); if (d < CHUNK) atomicAdd(&h[d], 1);
            d = (unsigned)(v.y - lo); if (d < CHUNK) atomicAdd(&h[d], 1);
            d = (unsigned)(v.z - lo); if (d < CHUNK) atomicAdd(&h[d], 1);
            d = (unsigned)(v.w - lo); if (d < CHUNK) atomicAdd(&h[d], 1);
        }
        for (int e = e0 + (nvec << 2) + threadIdx.x; e < e1; e += TPB) {
            unsigned d = (unsigned)(src[e] - lo);
            if (d < CHUNK) atomicAdd(&h[d], 1);
        }
    }
    __syncthreads();
    int* dstp = part + (size_t)b * CHUNK;
    for (int i = threadIdx.x; i < CHUNK; i += TPB) dstp[i] = h[i];
}

// dout[which*N + node] = sum over GPART partials
__global__ void histreduce_kernel(const int* __restrict__ part, int* __restrict__ dout,
                                  int N, int nchunk) {
    int i = blockIdx.x * TPB + threadIdx.x;
    if (i >= 2 * N) return;
    int which = i < N ? 0 : 1;
    int node  = which ? i - N : i;
    int chunk = node / CHUNK, off = node % CHUNK;
    const int* base = part + ((size_t)(which * nchunk + chunk) * GPART) * CHUNK + off;
    int s = 0;
    #pragma unroll
    for (int p = 0; p < GPART; p++) s += base[(size_t)p * CHUNK];
    dout[i] = s;
}

// ---------------- slack-bucket scatter: cursor atomic yields deg_in for free -----------
__global__ void scatter_kernel(const int* __restrict__ src, const int* __restrict__ dst,
                               int* __restrict__ cnt, int* __restrict__ esrc, int E) {
    int i = blockIdx.x * TPB + threadIdx.x;
    int e = i * 4;
    if (e + 3 < E) {
        int4 s = ((const int4*)src)[i];
        int4 d = ((const int4*)dst)[i];
        int r;
        r = atomicAdd(&cnt[d.x], 1); if (r < CAP) esrc[(size_t)d.x * CAP + r] = s.x;
        r = atomicAdd(&cnt[d.y], 1); if (r < CAP) esrc[(size_t)d.y * CAP + r] = s.y;
        r = atomicAdd(&cnt[d.z], 1); if (r < CAP) esrc[(size_t)d.z * CAP + r] = s.z;
        r = atomicAdd(&cnt[d.w], 1); if (r < CAP) esrc[(size_t)d.w * CAP + r] = s.w;
    } else {
        for (; e < E; e++) {
            int dd = dst[e];
            int r = atomicAdd(&cnt[dd], 1);
            if (r < CAP) esrc[(size_t)dd * CAP + r] = src[e];
        }
    }
}

// ---------------- GEMM 1: [N,128] @ [128,64]; epilogue -> two sout-scaled bf16 copies ---
__global__ void gemm1_kernel(const float* __restrict__ x, const float* __restrict__ W,
                             const int* __restrict__ dout1, const int* __restrict__ dout2,
                             unsigned short* __restrict__ Y0, unsigned short* __restrict__ Y1,
                             int N) {
    __shared__ float xs[64 * 128];   // 32 KB
    __shared__ float ws[128 * 64];   // 32 KB
    int tid  = threadIdx.x;
    int row0 = blockIdx.x * 64;
    for (int i = tid; i < 2048; i += TPB)
        ((float4*)ws)[i] = ((const float4*)W)[i];
    for (int i = tid; i < 2048; i += TPB) {
        int r = row0 + (i >> 5);
        ((float4*)xs)[i] = (r < N) ? ((const float4*)x)[(size_t)r * 32 + (i & 31)]
                                   : make_float4(0.f, 0.f, 0.f, 0.f);
    }
    __syncthreads();
    int tr = tid >> 4, tc = tid & 15;
    float acc[4][4] = {};
    for (int k4 = 0; k4 < 32; k4++) {
        float4 a[4], b[4];
        #pragma unroll
        for (int j = 0; j < 4; j++) a[j] = ((float4*)xs)[(tr * 4 + j) * 32 + k4];
        #pragma unroll
        for (int j = 0; j < 4; j++) b[j] = ((float4*)ws)[(k4 * 4 + j) * 16 + tc];
        #pragma unroll
        for (int i = 0; i < 4; i++) {
            float4 ai = a[i];
            acc[i][0] += ai.x * b[0].x + ai.y * b[1].x + ai.z * b[2].x + ai.w * b[3].x;
            acc[i][1] += ai.x * b[0].y + ai.y * b[1].y + ai.z * b[2].y + ai.w * b[3].y;
            acc[i][2] += ai.x * b[0].z + ai.y * b[1].z + ai.z * b[2].z + ai.w * b[3].z;
            acc[i][3] += ai.x * b[0].w + ai.y * b[1].w + ai.z * b[2].w + ai.w * b[3].w;
        }
    }
    #pragma unroll
    for (int i = 0; i < 4; i++) {
        int r = row0 + tr * 4 + i;
        if (r < N) {
            int g0 = dout1[r], g1 = dout2[r];
            float s0 = rsqrtf((float)(g0 > 1 ? g0 : 1));
            float s1 = rsqrtf((float)(g1 > 1 ? g1 : 1));
            size_t o = (size_t)r * 64 + tc * 4;
            ushort4 p0 = make_ushort4(f2bf(acc[i][0] * s0), f2bf(acc[i][1] * s0),
                                      f2bf(acc[i][2] * s0), f2bf(acc[i][3] * s0));
            ushort4 p1 = make_ushort4(f2bf(acc[i][0] * s1), f2bf(acc[i][1] * s1),
                                      f2bf(acc[i][2] * s1), f2bf(acc[i][3] * s1));
            *(ushort4*)(Y0 + o) = p0;
            *(ushort4*)(Y1 + o) = p1;
        }
    }
}

// ---------------- GEMM 2: H1[N,64] @ W2[64,32] -> sout-scaled bf16 H2[N,32] -------------
__global__ void gemm2_kernel(const float* __restrict__ H, const float* __restrict__ W,
                             const int* __restrict__ dout, unsigned short* __restrict__ H2,
                             int N) {
    __shared__ float xs[32 * 64];    // 8 KB
    __shared__ float ws[64 * 32];    // 8 KB
    int tid  = threadIdx.x;
    int row0 = blockIdx.x * 32;
    for (int i = tid; i < 512; i += TPB)
        ((float4*)ws)[i] = ((const float4*)W)[i];
    for (int i = tid; i < 512; i += TPB) {
        int r = row0 + (i >> 4);
        ((float4*)xs)[i] = (r < N) ? ((const float4*)H)[(size_t)r * 16 + (i & 15)]
                                   : make_float4(0.f, 0.f, 0.f, 0.f);
    }
    __syncthreads();
    int c  = tid & 31;
    int r0 = tid >> 5;
    for (int rr = 0; rr < 4; rr++) {
        int r = r0 + rr * 8;
        float acc = 0.f;
        #pragma unroll
        for (int k = 0; k < 64; k++) acc += xs[r * 64 + k] * ws[k * 32 + c];
        int grow = row0 + r;
        if (grow < N) {
            int g = dout[grow];
            float so = rsqrtf((float)(g > 1 ? g : 1));
            H2[(size_t)grow * 32 + c] = f2bf(acc * so);
        }
    }
}

// ---------------- layer-1 gather (bf16 rows, pre-scaled) + bias/relu ----------------
__global__ void agg1_kernel(const int* __restrict__ esrc, const int* __restrict__ cnt,
                            const unsigned short* __restrict__ Yg,
                            const float* __restrict__ b1, float* __restrict__ H1, int N) {
    int node = blockIdx.x * 4 + (threadIdx.x >> 6);
    int f = threadIdx.x & 63;
    if (node >= N) return;
    int dn = cnt[node];
    float si = rsqrtf((float)(dn > 1 ? dn : 1));
    if (dn > CAP) dn = CAP;
    const int* es = esrc + (size_t)node * CAP;
    float acc = 0.f;
    int i = 0;
    for (; i + 4 <= dn; i += 4) {
        int s0 = es[i], s1 = es[i + 1], s2 = es[i + 2], s3 = es[i + 3];
        acc += bf2f(Yg[(size_t)s0 * 64 + f]);
        acc += bf2f(Yg[(size_t)s1 * 64 + f]);
        acc += bf2f(Yg[(size_t)s2 * 64 + f]);
        acc += bf2f(Yg[(size_t)s3 * 64 + f]);
    }
    for (; i < dn; i++) acc += bf2f(Yg[(size_t)es[i] * 64 + f]);
    float v = acc * si + b1[f];
    H1[(size_t)node * 64 + f] = v > 0.f ? v : 0.f;
}

// ---------------- layer-2 gather (bf16 rows, pre-scaled) + mean epilogue ----------------
__global__ void agg2_kernel(const int* __restrict__ esrc, const int* __restrict__ cnt,
                            const unsigned short* __restrict__ H2,
                            const float* __restrict__ b2, float* __restrict__ out,
                            int N, int first) {
    int node = blockIdx.x * 8 + (threadIdx.x >> 5);
    int f = threadIdx.x & 31;
    if (node >= N) return;
    int dn = cnt[node];
    float si = rsqrtf((float)(dn > 1 ? dn : 1));
    if (dn > CAP) dn = CAP;
    const int* es = esrc + (size_t)node * CAP;
    float acc = 0.f;
    int i = 0;
    for (; i + 4 <= dn; i += 4) {
        int s0 = es[i], s1 = es[i + 1], s2 = es[i + 2], s3 = es[i + 3];
        acc += bf2f(H2[(size_t)s0 * 32 + f]);
        acc += bf2f(H2[(size_t)s1 * 32 + f]);
        acc += bf2f(H2[(size_t)s2 * 32 + f]);
        acc += bf2f(H2[(size_t)s3 * 32 + f]);
    }
    for (; i < dn; i++) acc += bf2f(H2[(size_t)es[i] * 32 + f]);
    float v = 0.5f * (acc * si + b2[f]);
    size_t o = (size_t)node * 32 + f;
    out[o] = first ? v : out[o] + v;
}

extern "C" void kernel_launch(void* const* d_in, const int* in_sizes, int n_in,
                              void* d_out, int out_size, void* d_ws, size_t ws_size,
                              hipStream_t stream) {
    const float* x    = (const float*)d_in[0];
    const int* srcs[2] = {(const int*)d_in[1], (const int*)d_in[3]};
    const int* dsts[2] = {(const int*)d_in[2], (const int*)d_in[4]};
    const float* W1   = (const float*)d_in[5];
    const float* b1   = (const float*)d_in[6];
    const float* W2   = (const float*)d_in[7];
    const float* b2   = (const float*)d_in[8];
    float* out        = (float*)d_out;

    const int N = in_sizes[0] / 128;   // 100000
    const int E = in_sizes[1];         // 1600000
    const int nchunk = (N + CHUNK - 1) / CHUNK;   // 13

    // byte layout (78.0 MB total):
    //   Y1G0 (bf16 64N) 12.8M | Y1G1 12.8M | H1 (f32 64N) 25.6M | H2 (bf16 32N) 6.4M
    //   | DOUT (2N int) 0.8M | CNT (N int) 0.4M | ESRC (CAP*N int) 19.2M
    // PART (2*nchunk*GPART*CHUNK ints = 27.3M) aliases [H1..H2] (32M), dead before agg1.
    unsigned short* Y1G0 = (unsigned short*)d_ws;
    unsigned short* Y1G1 = Y1G0 + (size_t)64 * N;
    float* H1            = (float*)(Y1G1 + (size_t)64 * N);
    unsigned short* H2   = (unsigned short*)(H1 + (size_t)64 * N);
    int* DOUT            = (int*)(H2 + (size_t)32 * N);
    int* CNT             = DOUT + (size_t)2 * N;
    int* ESRC            = CNT + N;
    int* PART            = (int*)H1;   // alias

    int eb4 = (E / 4 + TPB - 1) / TPB;

    // out-degrees without global atomics
    hist_kernel<<<2 * nchunk * GPART, TPB, 0, stream>>>(srcs[0], srcs[1], PART, N, E, nchunk);
    histreduce_kernel<<<(2 * N + TPB - 1) / TPB, TPB, 0, stream>>>(PART, DOUT, N, nchunk);

    gemm1_kernel<<<(N + 63) / 64, TPB, 0, stream>>>(x, W1, DOUT, DOUT + N, Y1G0, Y1G1, N);

    for (int g = 0; g < 2; g++) {
        const unsigned short* Yg = g == 0 ? Y1G0 : Y1G1;

        hipMemsetAsync(CNT, 0, sizeof(int) * (size_t)N, stream);
        scatter_kernel<<<eb4, TPB, 0, stream>>>(srcs[g], dsts[g], CNT, ESRC, E);

        agg1_kernel<<<(N + 3) / 4, TPB, 0, stream>>>(ESRC, CNT, Yg, b1, H1, N);
        gemm2_kernel<<<(N + 31) / 32, TPB, 0, stream>>>(H1, W2, DOUT + (size_t)g * N, H2, N);
        agg2_kernel<<<(N + 7) / 8, TPB, 0, stream>>>(ESRC, CNT, H2, b2, out, N, g == 0);
    }
}

// Round 7
// 463.524 us; speedup vs baseline: 2.8188x; 1.3144x over previous
//
#include <hip/hip_runtime.h>

#define TPB 256
#define CAP 48          // slack-bucket capacity (deg_in ~ Poisson(16))
#define CHUNK 8192      // nodes per LDS chunk (32 KB of int)
#define GPART 32        // edge-array partitions per chunk

__device__ inline unsigned short f2bf(float f) {
    union { float f; unsigned int u; } v; v.f = f;
    unsigned int u = v.u + 0x7FFFu + ((v.u >> 16) & 1u);   // RTNE
    return (unsigned short)(u >> 16);
}
__device__ inline float bf2f(unsigned short h) {
    union { unsigned int u; float f; } v; v.u = ((unsigned int)h) << 16;
    return v.f;
}

// ---------------- out-degree histograms for both src arrays (upfront) ----------------
__global__ void hist_kernel(const int* __restrict__ s1, const int* __restrict__ s2,
                            int* __restrict__ part, int N, int E, int nchunk) {
    __shared__ int h[CHUNK];
    int b     = blockIdx.x;
    int which = b / (nchunk * GPART);
    int rem   = b % (nchunk * GPART);
    int chunk = rem / GPART;
    int p     = rem % GPART;
    const int* src = which ? s2 : s1;

    for (int i = threadIdx.x; i < CHUNK; i += TPB) h[i] = 0;
    __syncthreads();

    int lo  = chunk * CHUNK;
    int per = ((E + GPART - 1) / GPART + 3) & ~3;
    int e0  = p * per;
    int e1  = e0 + per; if (e1 > E) e1 = E;
    if (e0 < e1) {
        int nvec = (e1 - e0) >> 2;
        const int4* vsrc = (const int4*)(src + e0);
        for (int i = threadIdx.x; i < nvec; i += TPB) {
            int4 v = vsrc[i];
            unsigned d;
            d = (unsigned)(v.x - lo); if (d < CHUNK) atomicAdd(&h[d], 1);
            d = (unsigned)(v.y - lo); if (d < CHUNK) atomicAdd(&h[d], 1);
            d = (unsigned)(v.z - lo); if (d < CHUNK) atomicAdd(&h[d], 1);
            d = (unsigned)(v.w - lo); if (d < CHUNK) atomicAdd(&h[d], 1);
        }
        for (int e = e0 + (nvec << 2) + threadIdx.x; e < e1; e += TPB) {
            unsigned d = (unsigned)(src[e] - lo);
            if (d < CHUNK) atomicAdd(&h[d], 1);
        }
    }
    __syncthreads();
    int* dstp = part + (size_t)b * CHUNK;
    for (int i = threadIdx.x; i < CHUNK; i += TPB) dstp[i] = h[i];
}

__global__ void histreduce_kernel(const int* __restrict__ part, int* __restrict__ dout,
                                  int N, int nchunk) {
    int i = blockIdx.x * TPB + threadIdx.x;
    if (i >= 2 * N) return;
    int which = i < N ? 0 : 1;
    int node  = which ? i - N : i;
    int chunk = node / CHUNK, off = node % CHUNK;
    const int* base = part + ((size_t)(which * nchunk + chunk) * GPART) * CHUNK + off;
    int s = 0;
    #pragma unroll
    for (int p = 0; p < GPART; p++) s += base[(size_t)p * CHUNK];
    dout[i] = s;
}

// ---------------- per-graph in-degree histogram (one array) ----------------
__global__ void hist1_kernel(const int* __restrict__ arr, int* __restrict__ part, int E) {
    __shared__ int h[CHUNK];
    int b     = blockIdx.x;
    int chunk = b / GPART;
    int p     = b % GPART;
    for (int i = threadIdx.x; i < CHUNK; i += TPB) h[i] = 0;
    __syncthreads();
    int lo  = chunk * CHUNK;
    int per = ((E + GPART - 1) / GPART + 3) & ~3;
    int e0  = p * per;
    int e1  = e0 + per; if (e1 > E) e1 = E;
    if (e0 < e1) {
        int nvec = (e1 - e0) >> 2;
        const int4* vsrc = (const int4*)(arr + e0);
        for (int i = threadIdx.x; i < nvec; i += TPB) {
            int4 v = vsrc[i];
            unsigned d;
            d = (unsigned)(v.x - lo); if (d < CHUNK) atomicAdd(&h[d], 1);
            d = (unsigned)(v.y - lo); if (d < CHUNK) atomicAdd(&h[d], 1);
            d = (unsigned)(v.z - lo); if (d < CHUNK) atomicAdd(&h[d], 1);
            d = (unsigned)(v.w - lo); if (d < CHUNK) atomicAdd(&h[d], 1);
        }
        for (int e = e0 + (nvec << 2) + threadIdx.x; e < e1; e += TPB) {
            unsigned d = (unsigned)(arr[e] - lo);
            if (d < CHUNK) atomicAdd(&h[d], 1);
        }
    }
    __syncthreads();
    int* dstp = part + (size_t)b * CHUNK;
    for (int i = threadIdx.x; i < CHUNK; i += TPB) dstp[i] = h[i];
}

// ---------------- counts -> per-partition exclusive offsets (in place); din for free ---
__global__ void offset_kernel(int* __restrict__ part, int* __restrict__ din, int N) {
    int n = blockIdx.x * TPB + threadIdx.x;
    if (n >= N) return;
    int c = n / CHUNK, o = n % CHUNK;
    int* base = part + ((size_t)c * GPART) * CHUNK + o;
    int run = n * CAP;
    #pragma unroll
    for (int p = 0; p < GPART; p++) {
        int t = base[(size_t)p * CHUNK];
        base[(size_t)p * CHUNK] = run;
        run += t;
    }
    din[n] = run - n * CAP;
}

// ---------------- scatter via LDS cursors: NO global atomics ----------------
__global__ void scatterC_kernel(const int* __restrict__ src, const int* __restrict__ dst,
                                const int* __restrict__ part, int* __restrict__ esrc, int E) {
    __shared__ int cur[CHUNK];
    int b     = blockIdx.x;
    int chunk = b / GPART;
    int p     = b % GPART;
    const int* offp = part + (size_t)b * CHUNK;
    for (int i = threadIdx.x; i < CHUNK; i += TPB) cur[i] = offp[i];
    __syncthreads();
    int lo  = chunk * CHUNK;
    int per = ((E + GPART - 1) / GPART + 3) & ~3;
    int e0  = p * per;
    int e1  = e0 + per; if (e1 > E) e1 = E;
    if (e0 < e1) {
        int nvec = (e1 - e0) >> 2;
        const int4* d4 = (const int4*)(dst + e0);
        const int4* s4 = (const int4*)(src + e0);
        for (int i = threadIdx.x; i < nvec; i += TPB) {
            int4 d = d4[i];
            int4 s = s4[i];
            unsigned u; int pos;
            u = (unsigned)(d.x - lo);
            if (u < CHUNK) { pos = atomicAdd(&cur[u], 1); if (pos < (lo + (int)u + 1) * CAP) esrc[pos] = s.x; }
            u = (unsigned)(d.y - lo);
            if (u < CHUNK) { pos = atomicAdd(&cur[u], 1); if (pos < (lo + (int)u + 1) * CAP) esrc[pos] = s.y; }
            u = (unsigned)(d.z - lo);
            if (u < CHUNK) { pos = atomicAdd(&cur[u], 1); if (pos < (lo + (int)u + 1) * CAP) esrc[pos] = s.z; }
            u = (unsigned)(d.w - lo);
            if (u < CHUNK) { pos = atomicAdd(&cur[u], 1); if (pos < (lo + (int)u + 1) * CAP) esrc[pos] = s.w; }
        }
        for (int e = e0 + (nvec << 2) + threadIdx.x; e < e1; e += TPB) {
            int dd = dst[e];
            unsigned u = (unsigned)(dd - lo);
            if (u < CHUNK) { int pos = atomicAdd(&cur[u], 1); if (pos < (dd + 1) * CAP) esrc[pos] = src[e]; }
        }
    }
}

// ---------------- GEMM 1: [N,128] @ [128,64]; epilogue -> two sout-scaled bf16 copies ---
__global__ void gemm1_kernel(const float* __restrict__ x, const float* __restrict__ W,
                             const int* __restrict__ dout1, const int* __restrict__ dout2,
                             unsigned short* __restrict__ Y0, unsigned short* __restrict__ Y1,
                             int N) {
    __shared__ float xs[64 * 128];   // 32 KB
    __shared__ float ws[128 * 64];   // 32 KB
    int tid  = threadIdx.x;
    int row0 = blockIdx.x * 64;
    for (int i = tid; i < 2048; i += TPB)
        ((float4*)ws)[i] = ((const float4*)W)[i];
    for (int i = tid; i < 2048; i += TPB) {
        int r = row0 + (i >> 5);
        ((float4*)xs)[i] = (r < N) ? ((const float4*)x)[(size_t)r * 32 + (i & 31)]
                                   : make_float4(0.f, 0.f, 0.f, 0.f);
    }
    __syncthreads();
    int tr = tid >> 4, tc = tid & 15;
    float acc[4][4] = {};
    for (int k4 = 0; k4 < 32; k4++) {
        float4 a[4], b[4];
        #pragma unroll
        for (int j = 0; j < 4; j++) a[j] = ((float4*)xs)[(tr * 4 + j) * 32 + k4];
        #pragma unroll
        for (int j = 0; j < 4; j++) b[j] = ((float4*)ws)[(k4 * 4 + j) * 16 + tc];
        #pragma unroll
        for (int i = 0; i < 4; i++) {
            float4 ai = a[i];
            acc[i][0] += ai.x * b[0].x + ai.y * b[1].x + ai.z * b[2].x + ai.w * b[3].x;
            acc[i][1] += ai.x * b[0].y + ai.y * b[1].y + ai.z * b[2].y + ai.w * b[3].y;
            acc[i][2] += ai.x * b[0].z + ai.y * b[1].z + ai.z * b[2].z + ai.w * b[3].z;
            acc[i][3] += ai.x * b[0].w + ai.y * b[1].w + ai.z * b[2].w + ai.w * b[3].w;
        }
    }
    #pragma unroll
    for (int i = 0; i < 4; i++) {
        int r = row0 + tr * 4 + i;
        if (r < N) {
            int g0 = dout1[r], g1 = dout2[r];
            float s0 = rsqrtf((float)(g0 > 1 ? g0 : 1));
            float s1 = rsqrtf((float)(g1 > 1 ? g1 : 1));
            size_t o = (size_t)r * 64 + tc * 4;
            ushort4 p0 = make_ushort4(f2bf(acc[i][0] * s0), f2bf(acc[i][1] * s0),
                                      f2bf(acc[i][2] * s0), f2bf(acc[i][3] * s0));
            ushort4 p1 = make_ushort4(f2bf(acc[i][0] * s1), f2bf(acc[i][1] * s1),
                                      f2bf(acc[i][2] * s1), f2bf(acc[i][3] * s1));
            *(ushort4*)(Y0 + o) = p0;
            *(ushort4*)(Y1 + o) = p1;
        }
    }
}

// ---------------- GEMM 2: H1[N,64] @ W2[64,32] -> sout-scaled bf16 H2[N,32] -------------
__global__ void gemm2_kernel(const float* __restrict__ H, const float* __restrict__ W,
                             const int* __restrict__ dout, unsigned short* __restrict__ H2,
                             int N) {
    __shared__ float xs[32 * 64];    // 8 KB
    __shared__ float ws[64 * 32];    // 8 KB
    int tid  = threadIdx.x;
    int row0 = blockIdx.x * 32;
    for (int i = tid; i < 512; i += TPB)
        ((float4*)ws)[i] = ((const float4*)W)[i];
    for (int i = tid; i < 512; i += TPB) {
        int r = row0 + (i >> 4);
        ((float4*)xs)[i] = (r < N) ? ((const float4*)H)[(size_t)r * 16 + (i & 15)]
                                   : make_float4(0.f, 0.f, 0.f, 0.f);
    }
    __syncthreads();
    int c  = tid & 31;
    int r0 = tid >> 5;
    for (int rr = 0; rr < 4; rr++) {
        int r = r0 + rr * 8;
        float acc = 0.f;
        #pragma unroll
        for (int k = 0; k < 64; k++) acc += xs[r * 64 + k] * ws[k * 32 + c];
        int grow = row0 + r;
        if (grow < N) {
            int g = dout[grow];
            float so = rsqrtf((float)(g > 1 ? g : 1));
            H2[(size_t)grow * 32 + c] = f2bf(acc * so);
        }
    }
}

// ---------------- layer-1 gather (bf16 rows, pre-scaled) + bias/relu ----------------
__global__ void agg1_kernel(const int* __restrict__ esrc, const int* __restrict__ din,
                            const unsigned short* __restrict__ Yg,
                            const float* __restrict__ b1, float* __restrict__ H1, int N) {
    int node = blockIdx.x * 4 + (threadIdx.x >> 6);
    int f = threadIdx.x & 63;
    if (node >= N) return;
    int dn = din[node];
    float si = rsqrtf((float)(dn > 1 ? dn : 1));
    if (dn > CAP) dn = CAP;
    const int* es = esrc + (size_t)node * CAP;
    float acc = 0.f;
    int i = 0;
    for (; i + 4 <= dn; i += 4) {
        int s0 = es[i], s1 = es[i + 1], s2 = es[i + 2], s3 = es[i + 3];
        acc += bf2f(Yg[(size_t)s0 * 64 + f]);
        acc += bf2f(Yg[(size_t)s1 * 64 + f]);
        acc += bf2f(Yg[(size_t)s2 * 64 + f]);
        acc += bf2f(Yg[(size_t)s3 * 64 + f]);
    }
    for (; i < dn; i++) acc += bf2f(Yg[(size_t)es[i] * 64 + f]);
    float v = acc * si + b1[f];
    H1[(size_t)node * 64 + f] = v > 0.f ? v : 0.f;
}

// ---------------- layer-2 gather (bf16 rows, pre-scaled) + mean epilogue ----------------
__global__ void agg2_kernel(const int* __restrict__ esrc, const int* __restrict__ din,
                            const unsigned short* __restrict__ H2,
                            const float* __restrict__ b2, float* __restrict__ out,
                            int N, int first) {
    int node = blockIdx.x * 8 + (threadIdx.x >> 5);
    int f = threadIdx.x & 31;
    if (node >= N) return;
    int dn = din[node];
    float si = rsqrtf((float)(dn > 1 ? dn : 1));
    if (dn > CAP) dn = CAP;
    const int* es = esrc + (size_t)node * CAP;
    float acc = 0.f;
    int i = 0;
    for (; i + 4 <= dn; i += 4) {
        int s0 = es[i], s1 = es[i + 1], s2 = es[i + 2], s3 = es[i + 3];
        acc += bf2f(H2[(size_t)s0 * 32 + f]);
        acc += bf2f(H2[(size_t)s1 * 32 + f]);
        acc += bf2f(H2[(size_t)s2 * 32 + f]);
        acc += bf2f(H2[(size_t)s3 * 32 + f]);
    }
    for (; i < dn; i++) acc += bf2f(H2[(size_t)es[i] * 32 + f]);
    float v = 0.5f * (acc * si + b2[f]);
    size_t o = (size_t)node * 32 + f;
    out[o] = first ? v : out[o] + v;
}

extern "C" void kernel_launch(void* const* d_in, const int* in_sizes, int n_in,
                              void* d_out, int out_size, void* d_ws, size_t ws_size,
                              hipStream_t stream) {
    const float* x    = (const float*)d_in[0];
    const int* srcs[2] = {(const int*)d_in[1], (const int*)d_in[3]};
    const int* dsts[2] = {(const int*)d_in[2], (const int*)d_in[4]};
    const float* W1   = (const float*)d_in[5];
    const float* b1   = (const float*)d_in[6];
    const float* W2   = (const float*)d_in[7];
    const float* b2   = (const float*)d_in[8];
    float* out        = (float*)d_out;

    const int N = in_sizes[0] / 128;   // 100000
    const int E = in_sizes[1];         // 1600000
    const int nchunk = (N + CHUNK - 1) / CHUNK;   // 13

    // byte layout (78.4 MB dedicated):
    //   Y1G0 (bf16 64N) 12.8M | Y1G1 12.8M | H1 (f32 64N) 25.6M | H2 (bf16 32N) 6.4M
    //   | DOUT (2N int) 0.8M | DIN (2N int) 0.8M | ESRC (CAP*N int) 19.2M
    // Aliases: PART2 (src hist, 27.3M) over H1+H2; PART1 (dst hist, 13.6M) over H1.
    // Both dead before their regions are written (gemm2 writes H2 after PART2 dies;
    // agg1 writes H1 after PART1's offsets are consumed by scatterC).
    unsigned short* Y1G0 = (unsigned short*)d_ws;
    unsigned short* Y1G1 = Y1G0 + (size_t)64 * N;
    float* H1            = (float*)(Y1G1 + (size_t)64 * N);
    unsigned short* H2   = (unsigned short*)(H1 + (size_t)64 * N);
    int* DOUT            = (int*)(H2 + (size_t)32 * N);
    int* DIN             = DOUT + (size_t)2 * N;
    int* ESRC            = DIN + (size_t)2 * N;
    int* PART2           = (int*)H1;
    int* PART1           = (int*)H1;

    // out-degrees for both graphs (no global atomics)
    hist_kernel<<<2 * nchunk * GPART, TPB, 0, stream>>>(srcs[0], srcs[1], PART2, N, E, nchunk);
    histreduce_kernel<<<(2 * N + TPB - 1) / TPB, TPB, 0, stream>>>(PART2, DOUT, N, nchunk);

    gemm1_kernel<<<(N + 63) / 64, TPB, 0, stream>>>(x, W1, DOUT, DOUT + N, Y1G0, Y1G1, N);

    for (int g = 0; g < 2; g++) {
        const unsigned short* Yg = g == 0 ? Y1G0 : Y1G1;
        int* din = DIN + (size_t)g * N;

        // CSR-ish slack buckets without any global atomics
        hist1_kernel<<<nchunk * GPART, TPB, 0, stream>>>(dsts[g], PART1, E);
        offset_kernel<<<(N + TPB - 1) / TPB, TPB, 0, stream>>>(PART1, din, N);
        scatterC_kernel<<<nchunk * GPART, TPB, 0, stream>>>(srcs[g], dsts[g], PART1, ESRC, E);

        agg1_kernel<<<(N + 3) / 4, TPB, 0, stream>>>(ESRC, din, Yg, b1, H1, N);
        gemm2_kernel<<<(N + 31) / 32, TPB, 0, stream>>>(H1, W2, DOUT + (size_t)g * N, H2, N);
        agg2_kernel<<<(N + 7) / 8, TPB, 0, stream>>>(ESRC, din, H2, b2, out, N, g == 0);
    }
}

// Round 9
// 405.626 us; speedup vs baseline: 3.2211x; 1.1427x over previous
//
#include <hip/hip_runtime.h>

#define TPB 256
#define CAP 48          // slack-bucket capacity (deg_in ~ Poisson(16))
#define CHUNK 16384     // nodes per LDS chunk (64 KB of int -> 2 blocks/CU)
#define GP1 64          // partitions for per-graph hist/scatter passes
#define GP2 32          // partitions for the dual-source out-degree hist (alias budget!)

__device__ inline unsigned short f2bf(float f) {
    union { float f; unsigned int u; } v; v.f = f;
    unsigned int u = v.u + 0x7FFFu + ((v.u >> 16) & 1u);   // RTNE
    return (unsigned short)(u >> 16);
}
__device__ inline float bf2f(unsigned short h) {
    union { unsigned int u; float f; } v; v.u = ((unsigned int)h) << 16;
    return v.f;
}

// ---------------- out-degree histograms for both src arrays (GP2 partitions) -----------
__global__ void hist_kernel(const int* __restrict__ s1, const int* __restrict__ s2,
                            int* __restrict__ part, int E, int nchunk) {
    __shared__ int h[CHUNK];
    int b     = blockIdx.x;
    int which = b / (nchunk * GP2);
    int rem   = b % (nchunk * GP2);
    int chunk = rem / GP2;
    int p     = rem % GP2;
    const int* src = which ? s2 : s1;

    for (int i = threadIdx.x; i < CHUNK; i += TPB) h[i] = 0;
    __syncthreads();

    int lo  = chunk * CHUNK;
    int per = ((E + GP2 - 1) / GP2 + 3) & ~3;
    int e0  = p * per;
    int e1  = e0 + per; if (e1 > E) e1 = E;
    if (e0 < e1) {
        int nvec = (e1 - e0) >> 2;
        const int4* vsrc = (const int4*)(src + e0);
        for (int i = threadIdx.x; i < nvec; i += TPB) {
            int4 v = vsrc[i];
            unsigned d;
            d = (unsigned)(v.x - lo); if (d < CHUNK) atomicAdd(&h[d], 1);
            d = (unsigned)(v.y - lo); if (d < CHUNK) atomicAdd(&h[d], 1);
            d = (unsigned)(v.z - lo); if (d < CHUNK) atomicAdd(&h[d], 1);
            d = (unsigned)(v.w - lo); if (d < CHUNK) atomicAdd(&h[d], 1);
        }
        for (int e = e0 + (nvec << 2) + threadIdx.x; e < e1; e += TPB) {
            unsigned d = (unsigned)(src[e] - lo);
            if (d < CHUNK) atomicAdd(&h[d], 1);
        }
    }
    __syncthreads();
    int* dstp = part + (size_t)b * CHUNK;
    for (int i = threadIdx.x; i < CHUNK; i += TPB) dstp[i] = h[i];
}

__global__ void histreduce_kernel(const int* __restrict__ part, int* __restrict__ dout,
                                  int N, int nchunk) {
    int i = blockIdx.x * TPB + threadIdx.x;
    if (i >= 2 * N) return;
    int which = i < N ? 0 : 1;
    int node  = which ? i - N : i;
    int chunk = node / CHUNK, off = node % CHUNK;
    const int* base = part + ((size_t)(which * nchunk + chunk) * GP2) * CHUNK + off;
    int s = 0;
    #pragma unroll
    for (int p = 0; p < GP2; p++) s += base[(size_t)p * CHUNK];
    dout[i] = s;
}

// ---------------- per-graph in-degree histogram (GP1 partitions) ----------------
__global__ void hist1_kernel(const int* __restrict__ arr, int* __restrict__ part, int E) {
    __shared__ int h[CHUNK];
    int b     = blockIdx.x;
    int chunk = b / GP1;
    int p     = b % GP1;
    for (int i = threadIdx.x; i < CHUNK; i += TPB) h[i] = 0;
    __syncthreads();
    int lo  = chunk * CHUNK;
    int per = ((E + GP1 - 1) / GP1 + 3) & ~3;
    int e0  = p * per;
    int e1  = e0 + per; if (e1 > E) e1 = E;
    if (e0 < e1) {
        int nvec = (e1 - e0) >> 2;
        const int4* vsrc = (const int4*)(arr + e0);
        for (int i = threadIdx.x; i < nvec; i += TPB) {
            int4 v = vsrc[i];
            unsigned d;
            d = (unsigned)(v.x - lo); if (d < CHUNK) atomicAdd(&h[d], 1);
            d = (unsigned)(v.y - lo); if (d < CHUNK) atomicAdd(&h[d], 1);
            d = (unsigned)(v.z - lo); if (d < CHUNK) atomicAdd(&h[d], 1);
            d = (unsigned)(v.w - lo); if (d < CHUNK) atomicAdd(&h[d], 1);
        }
        for (int e = e0 + (nvec << 2) + threadIdx.x; e < e1; e += TPB) {
            unsigned d = (unsigned)(arr[e] - lo);
            if (d < CHUNK) atomicAdd(&h[d], 1);
        }
    }
    __syncthreads();
    int* dstp = part + (size_t)b * CHUNK;
    for (int i = threadIdx.x; i < CHUNK; i += TPB) dstp[i] = h[i];
}

// ---------------- counts -> per-partition exclusive offsets (in place); din for free ---
__global__ void offset_kernel(int* __restrict__ part, int* __restrict__ din, int N) {
    int n = blockIdx.x * TPB + threadIdx.x;
    if (n >= N) return;
    int c = n / CHUNK, o = n % CHUNK;
    int* base = part + ((size_t)c * GP1) * CHUNK + o;
    int run = n * CAP;
    #pragma unroll
    for (int p = 0; p < GP1; p++) {
        int t = base[(size_t)p * CHUNK];
        base[(size_t)p * CHUNK] = run;
        run += t;
    }
    din[n] = run - n * CAP;
}

// ---------------- scatter via LDS cursors: NO global atomics ----------------
__global__ void scatterC_kernel(const int* __restrict__ src, const int* __restrict__ dst,
                                const int* __restrict__ part, int* __restrict__ esrc, int E) {
    __shared__ int cur[CHUNK];
    int b     = blockIdx.x;
    int chunk = b / GP1;
    int p     = b % GP1;
    const int* offp = part + (size_t)b * CHUNK;
    for (int i = threadIdx.x; i < CHUNK; i += TPB) cur[i] = offp[i];
    __syncthreads();
    int lo  = chunk * CHUNK;
    int per = ((E + GP1 - 1) / GP1 + 3) & ~3;
    int e0  = p * per;
    int e1  = e0 + per; if (e1 > E) e1 = E;
    if (e0 < e1) {
        int nvec = (e1 - e0) >> 2;
        const int4* d4 = (const int4*)(dst + e0);
        const int4* s4 = (const int4*)(src + e0);
        for (int i = threadIdx.x; i < nvec; i += TPB) {
            int4 d = d4[i];
            int4 s = s4[i];
            unsigned u; int pos;
            u = (unsigned)(d.x - lo);
            if (u < CHUNK) { pos = atomicAdd(&cur[u], 1); if (pos < (lo + (int)u + 1) * CAP) esrc[pos] = s.x; }
            u = (unsigned)(d.y - lo);
            if (u < CHUNK) { pos = atomicAdd(&cur[u], 1); if (pos < (lo + (int)u + 1) * CAP) esrc[pos] = s.y; }
            u = (unsigned)(d.z - lo);
            if (u < CHUNK) { pos = atomicAdd(&cur[u], 1); if (pos < (lo + (int)u + 1) * CAP) esrc[pos] = s.z; }
            u = (unsigned)(d.w - lo);
            if (u < CHUNK) { pos = atomicAdd(&cur[u], 1); if (pos < (lo + (int)u + 1) * CAP) esrc[pos] = s.w; }
        }
        for (int e = e0 + (nvec << 2) + threadIdx.x; e < e1; e += TPB) {
            int dd = dst[e];
            unsigned u = (unsigned)(dd - lo);
            if (u < CHUNK) { int pos = atomicAdd(&cur[u], 1); if (pos < (dd + 1) * CAP) esrc[pos] = src[e]; }
        }
    }
}

// ---------------- GEMM 1: [N,128] @ [128,64]; epilogue -> two sout-scaled bf16 copies ---
__global__ void gemm1_kernel(const float* __restrict__ x, const float* __restrict__ W,
                             const int* __restrict__ dout1, const int* __restrict__ dout2,
                             unsigned short* __restrict__ Y0, unsigned short* __restrict__ Y1,
                             int N) {
    __shared__ float xs[64 * 128];   // 32 KB
    __shared__ float ws[128 * 64];   // 32 KB
    int tid  = threadIdx.x;
    int row0 = blockIdx.x * 64;
    for (int i = tid; i < 2048; i += TPB)
        ((float4*)ws)[i] = ((const float4*)W)[i];
    for (int i = tid; i < 2048; i += TPB) {
        int r = row0 + (i >> 5);
        ((float4*)xs)[i] = (r < N) ? ((const float4*)x)[(size_t)r * 32 + (i & 31)]
                                   : make_float4(0.f, 0.f, 0.f, 0.f);
    }
    __syncthreads();
    int tr = tid >> 4, tc = tid & 15;
    float acc[4][4] = {};
    for (int k4 = 0; k4 < 32; k4++) {
        float4 a[4], b[4];
        #pragma unroll
        for (int j = 0; j < 4; j++) a[j] = ((float4*)xs)[(tr * 4 + j) * 32 + k4];
        #pragma unroll
        for (int j = 0; j < 4; j++) b[j] = ((float4*)ws)[(k4 * 4 + j) * 16 + tc];
        #pragma unroll
        for (int i = 0; i < 4; i++) {
            float4 ai = a[i];
            acc[i][0] += ai.x * b[0].x + ai.y * b[1].x + ai.z * b[2].x + ai.w * b[3].x;
            acc[i][1] += ai.x * b[0].y + ai.y * b[1].y + ai.z * b[2].y + ai.w * b[3].y;
            acc[i][2] += ai.x * b[0].z + ai.y * b[1].z + ai.z * b[2].z + ai.w * b[3].z;
            acc[i][3] += ai.x * b[0].w + ai.y * b[1].w + ai.z * b[2].w + ai.w * b[3].w;
        }
    }
    #pragma unroll
    for (int i = 0; i < 4; i++) {
        int r = row0 + tr * 4 + i;
        if (r < N) {
            int g0 = dout1[r], g1 = dout2[r];
            float s0 = rsqrtf((float)(g0 > 1 ? g0 : 1));
            float s1 = rsqrtf((float)(g1 > 1 ? g1 : 1));
            size_t o = (size_t)r * 64 + tc * 4;
            ushort4 p0 = make_ushort4(f2bf(acc[i][0] * s0), f2bf(acc[i][1] * s0),
                                      f2bf(acc[i][2] * s0), f2bf(acc[i][3] * s0));
            ushort4 p1 = make_ushort4(f2bf(acc[i][0] * s1), f2bf(acc[i][1] * s1),
                                      f2bf(acc[i][2] * s1), f2bf(acc[i][3] * s1));
            *(ushort4*)(Y0 + o) = p0;
            *(ushort4*)(Y1 + o) = p1;
        }
    }
}

// ---------------- GEMM 2: H1[N,64] @ W2[64,32] -> sout-scaled bf16 H2[N,32] -------------
__global__ void gemm2_kernel(const float* __restrict__ H, const float* __restrict__ W,
                             const int* __restrict__ dout, unsigned short* __restrict__ H2,
                             int N) {
    __shared__ float xs[32 * 64];    // 8 KB
    __shared__ float ws[64 * 32];    // 8 KB
    int tid  = threadIdx.x;
    int row0 = blockIdx.x * 32;
    for (int i = tid; i < 512; i += TPB)
        ((float4*)ws)[i] = ((const float4*)W)[i];
    for (int i = tid; i < 512; i += TPB) {
        int r = row0 + (i >> 4);
        ((float4*)xs)[i] = (r < N) ? ((const float4*)H)[(size_t)r * 16 + (i & 15)]
                                   : make_float4(0.f, 0.f, 0.f, 0.f);
    }
    __syncthreads();
    int c  = tid & 31;
    int r0 = tid >> 5;
    for (int rr = 0; rr < 4; rr++) {
        int r = r0 + rr * 8;
        float acc = 0.f;
        #pragma unroll
        for (int k = 0; k < 64; k++) acc += xs[r * 64 + k] * ws[k * 32 + c];
        int grow = row0 + r;
        if (grow < N) {
            int g = dout[grow];
            float so = rsqrtf((float)(g > 1 ? g : 1));
            H2[(size_t)grow * 32 + c] = f2bf(acc * so);
        }
    }
}

// ---------------- layer-1 gather (bf16 rows, pre-scaled) + bias/relu ----------------
__global__ void agg1_kernel(const int* __restrict__ esrc, const int* __restrict__ din,
                            const unsigned short* __restrict__ Yg,
                            const float* __restrict__ b1, float* __restrict__ H1, int N) {
    int node = blockIdx.x * 4 + (threadIdx.x >> 6);
    int f = threadIdx.x & 63;
    if (node >= N) return;
    int dn = din[node];
    float si = rsqrtf((float)(dn > 1 ? dn : 1));
    if (dn > CAP) dn = CAP;
    const int* es = esrc + (size_t)node * CAP;
    float acc = 0.f;
    int i = 0;
    for (; i + 8 <= dn; i += 8) {
        int4 a = *(const int4*)(es + i);
        int4 b = *(const int4*)(es + i + 4);
        acc += bf2f(Yg[(size_t)a.x * 64 + f]);
        acc += bf2f(Yg[(size_t)a.y * 64 + f]);
        acc += bf2f(Yg[(size_t)a.z * 64 + f]);
        acc += bf2f(Yg[(size_t)a.w * 64 + f]);
        acc += bf2f(Yg[(size_t)b.x * 64 + f]);
        acc += bf2f(Yg[(size_t)b.y * 64 + f]);
        acc += bf2f(Yg[(size_t)b.z * 64 + f]);
        acc += bf2f(Yg[(size_t)b.w * 64 + f]);
    }
    if (i + 4 <= dn) {
        int4 a = *(const int4*)(es + i);
        acc += bf2f(Yg[(size_t)a.x * 64 + f]);
        acc += bf2f(Yg[(size_t)a.y * 64 + f]);
        acc += bf2f(Yg[(size_t)a.z * 64 + f]);
        acc += bf2f(Yg[(size_t)a.w * 64 + f]);
        i += 4;
    }
    for (; i < dn; i++) acc += bf2f(Yg[(size_t)es[i] * 64 + f]);
    float v = acc * si + b1[f];
    H1[(size_t)node * 64 + f] = v > 0.f ? v : 0.f;
}

// ---------------- layer-2 gather (bf16 rows, pre-scaled) + mean epilogue ----------------
__global__ void agg2_kernel(const int* __restrict__ esrc, const int* __restrict__ din,
                            const unsigned short* __restrict__ H2,
                            const float* __restrict__ b2, float* __restrict__ out,
                            int N, int first) {
    int node = blockIdx.x * 8 + (threadIdx.x >> 5);
    int f = threadIdx.x & 31;
    if (node >= N) return;
    int dn = din[node];
    float si = rsqrtf((float)(dn > 1 ? dn : 1));
    if (dn > CAP) dn = CAP;
    const int* es = esrc + (size_t)node * CAP;
    float acc = 0.f;
    int i = 0;
    for (; i + 8 <= dn; i += 8) {
        int4 a = *(const int4*)(es + i);
        int4 b = *(const int4*)(es + i + 4);
        acc += bf2f(H2[(size_t)a.x * 32 + f]);
        acc += bf2f(H2[(size_t)a.y * 32 + f]);
        acc += bf2f(H2[(size_t)a.z * 32 + f]);
        acc += bf2f(H2[(size_t)a.w * 32 + f]);
        acc += bf2f(H2[(size_t)b.x * 32 + f]);
        acc += bf2f(H2[(size_t)b.y * 32 + f]);
        acc += bf2f(H2[(size_t)b.z * 32 + f]);
        acc += bf2f(H2[(size_t)b.w * 32 + f]);
    }
    if (i + 4 <= dn) {
        int4 a = *(const int4*)(es + i);
        acc += bf2f(H2[(size_t)a.x * 32 + f]);
        acc += bf2f(H2[(size_t)a.y * 32 + f]);
        acc += bf2f(H2[(size_t)a.z * 32 + f]);
        acc += bf2f(H2[(size_t)a.w * 32 + f]);
        i += 4;
    }
    for (; i < dn; i++) acc += bf2f(H2[(size_t)es[i] * 32 + f]);
    float v = 0.5f * (acc * si + b2[f]);
    size_t o = (size_t)node * 32 + f;
    out[o] = first ? v : out[o] + v;
}

extern "C" void kernel_launch(void* const* d_in, const int* in_sizes, int n_in,
                              void* d_out, int out_size, void* d_ws, size_t ws_size,
                              hipStream_t stream) {
    const float* x    = (const float*)d_in[0];
    const int* srcs[2] = {(const int*)d_in[1], (const int*)d_in[3]};
    const int* dsts[2] = {(const int*)d_in[2], (const int*)d_in[4]};
    const float* W1   = (const float*)d_in[5];
    const float* b1   = (const float*)d_in[6];
    const float* W2   = (const float*)d_in[7];
    const float* b2   = (const float*)d_in[8];
    float* out        = (float*)d_out;

    const int N = in_sizes[0] / 128;   // 100000
    const int E = in_sizes[1];         // 1600000
    const int nchunk = (N + CHUNK - 1) / CHUNK;   // 7

    // byte layout (78.4 MB dedicated):
    //   Y1G0 (bf16 64N) 12.8M | Y1G1 12.8M | H1 (f32 64N) 25.6M | H2 (bf16 32N) 6.4M
    //   | DOUT (2N int) 0.8M | DIN (2N int) 0.8M | ESRC (CAP*N int) 19.2M
    // Aliases (sizes recomputed for CHUNK=16384, N=100000, nchunk=7):
    //   PART2 = 2*7*GP2*CHUNK ints = 2*7*32*16384*4B = 29.36 MB over [Y1G0|Y1G1|H1 head]
    //     (51.2 MB window; dead before gemm1 writes Y1G0/Y1G1 — histreduce consumed it).
    //   PART1 = 7*GP1*CHUNK ints = 7*64*16384*4B = 29.36 MB over [H1|H2] (32.0 MB window;
    //     consumed by scatterC before agg1 writes H1 / gemm2 writes H2).
    unsigned short* Y1G0 = (unsigned short*)d_ws;
    unsigned short* Y1G1 = Y1G0 + (size_t)64 * N;
    float* H1            = (float*)(Y1G1 + (size_t)64 * N);
    unsigned short* H2   = (unsigned short*)(H1 + (size_t)64 * N);
    int* DOUT            = (int*)(H2 + (size_t)32 * N);
    int* DIN             = DOUT + (size_t)2 * N;
    int* ESRC            = DIN + (size_t)2 * N;
    int* PART2           = (int*)d_ws;
    int* PART1           = (int*)H1;

    // out-degrees for both graphs (no global atomics)
    hist_kernel<<<2 * nchunk * GP2, TPB, 0, stream>>>(srcs[0], srcs[1], PART2, E, nchunk);
    histreduce_kernel<<<(2 * N + TPB - 1) / TPB, TPB, 0, stream>>>(PART2, DOUT, N, nchunk);

    gemm1_kernel<<<(N + 63) / 64, TPB, 0, stream>>>(x, W1, DOUT, DOUT + N, Y1G0, Y1G1, N);

    for (int g = 0; g < 2; g++) {
        const unsigned short* Yg = g == 0 ? Y1G0 : Y1G1;
        int* din = DIN + (size_t)g * N;

        // slack-bucket CSR without any global atomics
        hist1_kernel<<<nchunk * GP1, TPB, 0, stream>>>(dsts[g], PART1, E);
        offset_kernel<<<(N + TPB - 1) / TPB, TPB, 0, stream>>>(PART1, din, N);
        scatterC_kernel<<<nchunk * GP1, TPB, 0, stream>>>(srcs[g], dsts[g], PART1, ESRC, E);

        agg1_kernel<<<(N + 3) / 4, TPB, 0, stream>>>(ESRC, din, Yg, b1, H1, N);
        gemm2_kernel<<<(N + 31) / 32, TPB, 0, stream>>>(H1, W2, DOUT + (size_t)g * N, H2, N);
        agg2_kernel<<<(N + 7) / 8, TPB, 0, stream>>>(ESRC, din, H2, b2, out, N, g == 0);
    }
}

// Round 10
// 385.514 us; speedup vs baseline: 3.3891x; 1.0522x over previous
//
#include <hip/hip_runtime.h>

#define TPB 256
#define CAP 48          // slack-bucket capacity (deg_in ~ Poisson(16))
#define CHUNK 16384     // nodes per LDS chunk (64 KB of int -> 2 blocks/CU)
#define GP1 64          // partitions for per-graph hist/scatter passes
#define GP2 32          // partitions for the dual-source out-degree hist (alias budget!)

__device__ inline unsigned short f2bf(float f) {
    union { float f; unsigned int u; } v; v.f = f;
    unsigned int u = v.u + 0x7FFFu + ((v.u >> 16) & 1u);   // RTNE
    return (unsigned short)(u >> 16);
}
__device__ inline float bf2f(unsigned short h) {
    union { unsigned int u; float f; } v; v.u = ((unsigned int)h) << 16;
    return v.f;
}

// ---------------- out-degree histograms for both src arrays (GP2 partitions) -----------
__global__ void hist_kernel(const int* __restrict__ s1, const int* __restrict__ s2,
                            int* __restrict__ part, int E, int nchunk) {
    __shared__ int h[CHUNK];
    int b     = blockIdx.x;
    int which = b / (nchunk * GP2);
    int rem   = b % (nchunk * GP2);
    int chunk = rem / GP2;
    int p     = rem % GP2;
    const int* src = which ? s2 : s1;

    for (int i = threadIdx.x; i < CHUNK; i += TPB) h[i] = 0;
    __syncthreads();

    int lo  = chunk * CHUNK;
    int per = ((E + GP2 - 1) / GP2 + 3) & ~3;
    int e0  = p * per;
    int e1  = e0 + per; if (e1 > E) e1 = E;
    if (e0 < e1) {
        int nvec = (e1 - e0) >> 2;
        const int4* vsrc = (const int4*)(src + e0);
        for (int i = threadIdx.x; i < nvec; i += TPB) {
            int4 v = vsrc[i];
            unsigned d;
            d = (unsigned)(v.x - lo); if (d < CHUNK) atomicAdd(&h[d], 1);
            d = (unsigned)(v.y - lo); if (d < CHUNK) atomicAdd(&h[d], 1);
            d = (unsigned)(v.z - lo); if (d < CHUNK) atomicAdd(&h[d], 1);
            d = (unsigned)(v.w - lo); if (d < CHUNK) atomicAdd(&h[d], 1);
        }
        for (int e = e0 + (nvec << 2) + threadIdx.x; e < e1; e += TPB) {
            unsigned d = (unsigned)(src[e] - lo);
            if (d < CHUNK) atomicAdd(&h[d], 1);
        }
    }
    __syncthreads();
    int* dstp = part + (size_t)b * CHUNK;
    for (int i = threadIdx.x; i < CHUNK; i += TPB) dstp[i] = h[i];
}

__global__ void histreduce_kernel(const int* __restrict__ part, int* __restrict__ dout,
                                  int N, int nchunk) {
    int i = blockIdx.x * TPB + threadIdx.x;
    if (i >= 2 * N) return;
    int which = i < N ? 0 : 1;
    int node  = which ? i - N : i;
    int chunk = node / CHUNK, off = node % CHUNK;
    const int* base = part + ((size_t)(which * nchunk + chunk) * GP2) * CHUNK + off;
    int s = 0;
    #pragma unroll
    for (int p = 0; p < GP2; p++) s += base[(size_t)p * CHUNK];
    dout[i] = s;
}

// ---------------- per-graph in-degree histogram (GP1 partitions) ----------------
__global__ void hist1_kernel(const int* __restrict__ arr, int* __restrict__ part, int E) {
    __shared__ int h[CHUNK];
    int b     = blockIdx.x;
    int chunk = b / GP1;
    int p     = b % GP1;
    for (int i = threadIdx.x; i < CHUNK; i += TPB) h[i] = 0;
    __syncthreads();
    int lo  = chunk * CHUNK;
    int per = ((E + GP1 - 1) / GP1 + 3) & ~3;
    int e0  = p * per;
    int e1  = e0 + per; if (e1 > E) e1 = E;
    if (e0 < e1) {
        int nvec = (e1 - e0) >> 2;
        const int4* vsrc = (const int4*)(arr + e0);
        for (int i = threadIdx.x; i < nvec; i += TPB) {
            int4 v = vsrc[i];
            unsigned d;
            d = (unsigned)(v.x - lo); if (d < CHUNK) atomicAdd(&h[d], 1);
            d = (unsigned)(v.y - lo); if (d < CHUNK) atomicAdd(&h[d], 1);
            d = (unsigned)(v.z - lo); if (d < CHUNK) atomicAdd(&h[d], 1);
            d = (unsigned)(v.w - lo); if (d < CHUNK) atomicAdd(&h[d], 1);
        }
        for (int e = e0 + (nvec << 2) + threadIdx.x; e < e1; e += TPB) {
            unsigned d = (unsigned)(arr[e] - lo);
            if (d < CHUNK) atomicAdd(&h[d], 1);
        }
    }
    __syncthreads();
    int* dstp = part + (size_t)b * CHUNK;
    for (int i = threadIdx.x; i < CHUNK; i += TPB) dstp[i] = h[i];
}

// ---------------- counts -> per-partition exclusive offsets (in place); din for free ---
__global__ void offset_kernel(int* __restrict__ part, int* __restrict__ din, int N) {
    int n = blockIdx.x * TPB + threadIdx.x;
    if (n >= N) return;
    int c = n / CHUNK, o = n % CHUNK;
    int* base = part + ((size_t)c * GP1) * CHUNK + o;
    int run = n * CAP;
    #pragma unroll
    for (int p = 0; p < GP1; p++) {
        int t = base[(size_t)p * CHUNK];
        base[(size_t)p * CHUNK] = run;
        run += t;
    }
    din[n] = run - n * CAP;
}

// ---------------- scatter via LDS cursors: NO global atomics ----------------
__global__ void scatterC_kernel(const int* __restrict__ src, const int* __restrict__ dst,
                                const int* __restrict__ part, int* __restrict__ esrc, int E) {
    __shared__ int cur[CHUNK];
    int b     = blockIdx.x;
    int chunk = b / GP1;
    int p     = b % GP1;
    const int* offp = part + (size_t)b * CHUNK;
    for (int i = threadIdx.x; i < CHUNK; i += TPB) cur[i] = offp[i];
    __syncthreads();
    int lo  = chunk * CHUNK;
    int per = ((E + GP1 - 1) / GP1 + 3) & ~3;
    int e0  = p * per;
    int e1  = e0 + per; if (e1 > E) e1 = E;
    if (e0 < e1) {
        int nvec = (e1 - e0) >> 2;
        const int4* d4 = (const int4*)(dst + e0);
        const int4* s4 = (const int4*)(src + e0);
        for (int i = threadIdx.x; i < nvec; i += TPB) {
            int4 d = d4[i];
            int4 s = s4[i];
            unsigned u; int pos;
            u = (unsigned)(d.x - lo);
            if (u < CHUNK) { pos = atomicAdd(&cur[u], 1); if (pos < (lo + (int)u + 1) * CAP) esrc[pos] = s.x; }
            u = (unsigned)(d.y - lo);
            if (u < CHUNK) { pos = atomicAdd(&cur[u], 1); if (pos < (lo + (int)u + 1) * CAP) esrc[pos] = s.y; }
            u = (unsigned)(d.z - lo);
            if (u < CHUNK) { pos = atomicAdd(&cur[u], 1); if (pos < (lo + (int)u + 1) * CAP) esrc[pos] = s.z; }
            u = (unsigned)(d.w - lo);
            if (u < CHUNK) { pos = atomicAdd(&cur[u], 1); if (pos < (lo + (int)u + 1) * CAP) esrc[pos] = s.w; }
        }
        for (int e = e0 + (nvec << 2) + threadIdx.x; e < e1; e += TPB) {
            int dd = dst[e];
            unsigned u = (unsigned)(dd - lo);
            if (u < CHUNK) { int pos = atomicAdd(&cur[u], 1); if (pos < (dd + 1) * CAP) esrc[pos] = src[e]; }
        }
    }
}

// ---------------- GEMM 1: [N,128] @ [128,64]; epilogue -> two sout-scaled bf16 copies ---
__global__ void gemm1_kernel(const float* __restrict__ x, const float* __restrict__ W,
                             const int* __restrict__ dout1, const int* __restrict__ dout2,
                             unsigned short* __restrict__ Y0, unsigned short* __restrict__ Y1,
                             int N) {
    __shared__ float xs[64 * 128];   // 32 KB
    __shared__ float ws[128 * 64];   // 32 KB
    int tid  = threadIdx.x;
    int row0 = blockIdx.x * 64;
    for (int i = tid; i < 2048; i += TPB)
        ((float4*)ws)[i] = ((const float4*)W)[i];
    for (int i = tid; i < 2048; i += TPB) {
        int r = row0 + (i >> 5);
        ((float4*)xs)[i] = (r < N) ? ((const float4*)x)[(size_t)r * 32 + (i & 31)]
                                   : make_float4(0.f, 0.f, 0.f, 0.f);
    }
    __syncthreads();
    int tr = tid >> 4, tc = tid & 15;
    float acc[4][4] = {};
    for (int k4 = 0; k4 < 32; k4++) {
        float4 a[4], b[4];
        #pragma unroll
        for (int j = 0; j < 4; j++) a[j] = ((float4*)xs)[(tr * 4 + j) * 32 + k4];
        #pragma unroll
        for (int j = 0; j < 4; j++) b[j] = ((float4*)ws)[(k4 * 4 + j) * 16 + tc];
        #pragma unroll
        for (int i = 0; i < 4; i++) {
            float4 ai = a[i];
            acc[i][0] += ai.x * b[0].x + ai.y * b[1].x + ai.z * b[2].x + ai.w * b[3].x;
            acc[i][1] += ai.x * b[0].y + ai.y * b[1].y + ai.z * b[2].y + ai.w * b[3].y;
            acc[i][2] += ai.x * b[0].z + ai.y * b[1].z + ai.z * b[2].z + ai.w * b[3].z;
            acc[i][3] += ai.x * b[0].w + ai.y * b[1].w + ai.z * b[2].w + ai.w * b[3].w;
        }
    }
    #pragma unroll
    for (int i = 0; i < 4; i++) {
        int r = row0 + tr * 4 + i;
        if (r < N) {
            int g0 = dout1[r], g1 = dout2[r];
            float s0 = rsqrtf((float)(g0 > 1 ? g0 : 1));
            float s1 = rsqrtf((float)(g1 > 1 ? g1 : 1));
            size_t o = (size_t)r * 64 + tc * 4;
            ushort4 p0 = make_ushort4(f2bf(acc[i][0] * s0), f2bf(acc[i][1] * s0),
                                      f2bf(acc[i][2] * s0), f2bf(acc[i][3] * s0));
            ushort4 p1 = make_ushort4(f2bf(acc[i][0] * s1), f2bf(acc[i][1] * s1),
                                      f2bf(acc[i][2] * s1), f2bf(acc[i][3] * s1));
            *(ushort4*)(Y0 + o) = p0;
            *(ushort4*)(Y1 + o) = p1;
        }
    }
}

// ---------------- FUSED layer-1 gather + bias/relu + @W2 + sout scale -> bf16 H2 -------
// one wave per node; lane f in 0..63 holds h[f]; epilogue does h@W2 in-wave.
__global__ void agg1f_kernel(const int* __restrict__ esrc, const int* __restrict__ din,
                             const unsigned short* __restrict__ Yg,
                             const float* __restrict__ b1, const float* __restrict__ W2,
                             const int* __restrict__ doutg,
                             unsigned short* __restrict__ H2, int N) {
    __shared__ float ws2[64 * 32];   // 8 KB, W2 staged
    __shared__ float hs[4][64];      // per-wave h row
    int tid = threadIdx.x;
    for (int i = tid; i < 512; i += TPB)
        ((float4*)ws2)[i] = ((const float4*)W2)[i];
    __syncthreads();

    int w    = tid >> 6;
    int f    = tid & 63;
    int node = blockIdx.x * 4 + w;
    if (node >= N) return;

    int dn = din[node];
    float si = rsqrtf((float)(dn > 1 ? dn : 1));
    if (dn > CAP) dn = CAP;
    const int* es = esrc + (size_t)node * CAP;
    float acc = 0.f;
    int i = 0;
    for (; i + 8 <= dn; i += 8) {
        int4 a = *(const int4*)(es + i);
        int4 b = *(const int4*)(es + i + 4);
        acc += bf2f(Yg[(size_t)a.x * 64 + f]);
        acc += bf2f(Yg[(size_t)a.y * 64 + f]);
        acc += bf2f(Yg[(size_t)a.z * 64 + f]);
        acc += bf2f(Yg[(size_t)a.w * 64 + f]);
        acc += bf2f(Yg[(size_t)b.x * 64 + f]);
        acc += bf2f(Yg[(size_t)b.y * 64 + f]);
        acc += bf2f(Yg[(size_t)b.z * 64 + f]);
        acc += bf2f(Yg[(size_t)b.w * 64 + f]);
    }
    if (i + 4 <= dn) {
        int4 a = *(const int4*)(es + i);
        acc += bf2f(Yg[(size_t)a.x * 64 + f]);
        acc += bf2f(Yg[(size_t)a.y * 64 + f]);
        acc += bf2f(Yg[(size_t)a.z * 64 + f]);
        acc += bf2f(Yg[(size_t)a.w * 64 + f]);
        i += 4;
    }
    for (; i < dn; i++) acc += bf2f(Yg[(size_t)es[i] * 64 + f]);

    float h = acc * si + b1[f];
    h = h > 0.f ? h : 0.f;
    hs[w][f] = h;                       // wave-internal LDS ordering suffices

    // epilogue: out[c] = sum_f hs[f] * W2[f][c]; lane c does f=0..31, lane c+32 f=32..63
    int half = f >> 5;
    int c    = f & 31;
    const float* hrow = hs[w] + half * 32;
    const float* wrow = ws2 + half * 32 * 32;
    float part = 0.f;
    #pragma unroll
    for (int k = 0; k < 32; k++) part += hrow[k] * wrow[k * 32 + c];
    float total = part + __shfl_xor(part, 32);
    if (half == 0) {
        int g = doutg[node];
        float so = rsqrtf((float)(g > 1 ? g : 1));
        H2[(size_t)node * 32 + c] = f2bf(total * so);
    }
}

// ---------------- layer-2 gather (bf16 rows, pre-scaled) + mean epilogue ----------------
__global__ void agg2_kernel(const int* __restrict__ esrc, const int* __restrict__ din,
                            const unsigned short* __restrict__ H2,
                            const float* __restrict__ b2, float* __restrict__ out,
                            int N, int first) {
    int node = blockIdx.x * 8 + (threadIdx.x >> 5);
    int f = threadIdx.x & 31;
    if (node >= N) return;
    int dn = din[node];
    float si = rsqrtf((float)(dn > 1 ? dn : 1));
    if (dn > CAP) dn = CAP;
    const int* es = esrc + (size_t)node * CAP;
    float acc = 0.f;
    int i = 0;
    for (; i + 8 <= dn; i += 8) {
        int4 a = *(const int4*)(es + i);
        int4 b = *(const int4*)(es + i + 4);
        acc += bf2f(H2[(size_t)a.x * 32 + f]);
        acc += bf2f(H2[(size_t)a.y * 32 + f]);
        acc += bf2f(H2[(size_t)a.z * 32 + f]);
        acc += bf2f(H2[(size_t)a.w * 32 + f]);
        acc += bf2f(H2[(size_t)b.x * 32 + f]);
        acc += bf2f(H2[(size_t)b.y * 32 + f]);
        acc += bf2f(H2[(size_t)b.z * 32 + f]);
        acc += bf2f(H2[(size_t)b.w * 32 + f]);
    }
    if (i + 4 <= dn) {
        int4 a = *(const int4*)(es + i);
        acc += bf2f(H2[(size_t)a.x * 32 + f]);
        acc += bf2f(H2[(size_t)a.y * 32 + f]);
        acc += bf2f(H2[(size_t)a.z * 32 + f]);
        acc += bf2f(H2[(size_t)a.w * 32 + f]);
        i += 4;
    }
    for (; i < dn; i++) acc += bf2f(H2[(size_t)es[i] * 32 + f]);
    float v = 0.5f * (acc * si + b2[f]);
    size_t o = (size_t)node * 32 + f;
    out[o] = first ? v : out[o] + v;
}

extern "C" void kernel_launch(void* const* d_in, const int* in_sizes, int n_in,
                              void* d_out, int out_size, void* d_ws, size_t ws_size,
                              hipStream_t stream) {
    const float* x    = (const float*)d_in[0];
    const int* srcs[2] = {(const int*)d_in[1], (const int*)d_in[3]};
    const int* dsts[2] = {(const int*)d_in[2], (const int*)d_in[4]};
    const float* W1   = (const float*)d_in[5];
    const float* b1   = (const float*)d_in[6];
    const float* W2   = (const float*)d_in[7];
    const float* b2   = (const float*)d_in[8];
    float* out        = (float*)d_out;

    const int N = in_sizes[0] / 128;   // 100000
    const int E = in_sizes[1];         // 1600000
    const int nchunk = (N + CHUNK - 1) / CHUNK;   // 7

    // byte layout (78.4 MB dedicated):
    //   Y1G0 (bf16 64N) 12.8M | Y1G1 12.8M | SCR 25.6M | H2 (bf16 32N) 6.4M
    //   | DOUT (2N int) 0.8M | DIN (2N int) 0.8M | ESRC (CAP*N int) 19.2M
    // Aliases (recomputed, CHUNK=16384, nchunk=7):
    //   PART2 = 2*7*GP2*CHUNK*4B = 29.36 MB over [Y1G0|Y1G1|SCR head] (51.2 MB window;
    //     consumed by histreduce before gemm1 writes Y1G0/Y1G1).
    //   PART1 = 7*GP1*CHUNK*4B = 29.36 MB over [SCR|H2] (32.0 MB window; consumed by
    //     scatterC before agg1f writes H2).
    unsigned short* Y1G0 = (unsigned short*)d_ws;
    unsigned short* Y1G1 = Y1G0 + (size_t)64 * N;
    float* SCR           = (float*)(Y1G1 + (size_t)64 * N);
    unsigned short* H2   = (unsigned short*)(SCR + (size_t)64 * N);
    int* DOUT            = (int*)(H2 + (size_t)32 * N);
    int* DIN             = DOUT + (size_t)2 * N;
    int* ESRC            = DIN + (size_t)2 * N;
    int* PART2           = (int*)d_ws;
    int* PART1           = (int*)SCR;

    // out-degrees for both graphs (no global atomics)
    hist_kernel<<<2 * nchunk * GP2, TPB, 0, stream>>>(srcs[0], srcs[1], PART2, E, nchunk);
    histreduce_kernel<<<(2 * N + TPB - 1) / TPB, TPB, 0, stream>>>(PART2, DOUT, N, nchunk);

    gemm1_kernel<<<(N + 63) / 64, TPB, 0, stream>>>(x, W1, DOUT, DOUT + N, Y1G0, Y1G1, N);

    for (int g = 0; g < 2; g++) {
        const unsigned short* Yg = g == 0 ? Y1G0 : Y1G1;
        int* din = DIN + (size_t)g * N;

        // slack-bucket CSR without any global atomics
        hist1_kernel<<<nchunk * GP1, TPB, 0, stream>>>(dsts[g], PART1, E);
        offset_kernel<<<(N + TPB - 1) / TPB, TPB, 0, stream>>>(PART1, din, N);
        scatterC_kernel<<<nchunk * GP1, TPB, 0, stream>>>(srcs[g], dsts[g], PART1, ESRC, E);

        agg1f_kernel<<<(N + 3) / 4, TPB, 0, stream>>>(ESRC, din, Yg, b1, W2,
                                                      DOUT + (size_t)g * N, H2, N);
        agg2_kernel<<<(N + 7) / 8, TPB, 0, stream>>>(ESRC, din, H2, b2, out, N, g == 0);
    }
}

// Round 11
// 368.083 us; speedup vs baseline: 3.5496x; 1.0474x over previous
//
#include <hip/hip_runtime.h>

#define TPB 256
#define CAP 48          // slack-bucket capacity (deg_in ~ Poisson(16))
#define CHUNK 16384     // nodes per LDS chunk (64 KB of int -> 2 blocks/CU)
#define GP1 64          // partitions for per-graph hist/scatter passes
#define GP2 32          // partitions for the dual-source out-degree hist (alias budget!)

__device__ inline unsigned short f2bf(float f) {
    union { float f; unsigned int u; } v; v.f = f;
    unsigned int u = v.u + 0x7FFFu + ((v.u >> 16) & 1u);   // RTNE
    return (unsigned short)(u >> 16);
}
__device__ inline float bf2f(unsigned short h) {
    union { unsigned int u; float f; } v; v.u = ((unsigned int)h) << 16;
    return v.f;
}
__device__ inline float bflo(unsigned int v) {        // low bf16 of packed pair
    union { unsigned int u; float f; } w; w.u = v << 16;
    return w.f;
}
__device__ inline float bfhi(unsigned int v) {        // high bf16 of packed pair
    union { unsigned int u; float f; } w; w.u = v & 0xffff0000u;
    return w.f;
}

// ---------------- out-degree histograms for both src arrays (GP2 partitions) -----------
__global__ void hist_kernel(const int* __restrict__ s1, const int* __restrict__ s2,
                            int* __restrict__ part, int E, int nchunk) {
    __shared__ int h[CHUNK];
    int b     = blockIdx.x;
    int which = b / (nchunk * GP2);
    int rem   = b % (nchunk * GP2);
    int chunk = rem / GP2;
    int p     = rem % GP2;
    const int* src = which ? s2 : s1;

    for (int i = threadIdx.x; i < CHUNK; i += TPB) h[i] = 0;
    __syncthreads();

    int lo  = chunk * CHUNK;
    int per = ((E + GP2 - 1) / GP2 + 3) & ~3;
    int e0  = p * per;
    int e1  = e0 + per; if (e1 > E) e1 = E;
    if (e0 < e1) {
        int nvec = (e1 - e0) >> 2;
        const int4* vsrc = (const int4*)(src + e0);
        for (int i = threadIdx.x; i < nvec; i += TPB) {
            int4 v = vsrc[i];
            unsigned d;
            d = (unsigned)(v.x - lo); if (d < CHUNK) atomicAdd(&h[d], 1);
            d = (unsigned)(v.y - lo); if (d < CHUNK) atomicAdd(&h[d], 1);
            d = (unsigned)(v.z - lo); if (d < CHUNK) atomicAdd(&h[d], 1);
            d = (unsigned)(v.w - lo); if (d < CHUNK) atomicAdd(&h[d], 1);
        }
        for (int e = e0 + (nvec << 2) + threadIdx.x; e < e1; e += TPB) {
            unsigned d = (unsigned)(src[e] - lo);
            if (d < CHUNK) atomicAdd(&h[d], 1);
        }
    }
    __syncthreads();
    int* dstp = part + (size_t)b * CHUNK;
    for (int i = threadIdx.x; i < CHUNK; i += TPB) dstp[i] = h[i];
}

__global__ void histreduce_kernel(const int* __restrict__ part, int* __restrict__ dout,
                                  int N, int nchunk) {
    int i = blockIdx.x * TPB + threadIdx.x;
    if (i >= 2 * N) return;
    int which = i < N ? 0 : 1;
    int node  = which ? i - N : i;
    int chunk = node / CHUNK, off = node % CHUNK;
    const int* base = part + ((size_t)(which * nchunk + chunk) * GP2) * CHUNK + off;
    int s = 0;
    #pragma unroll
    for (int p = 0; p < GP2; p++) s += base[(size_t)p * CHUNK];
    dout[i] = s;
}

// ---------------- per-graph in-degree histogram (GP1 partitions) ----------------
__global__ void hist1_kernel(const int* __restrict__ arr, int* __restrict__ part, int E) {
    __shared__ int h[CHUNK];
    int b     = blockIdx.x;
    int chunk = b / GP1;
    int p     = b % GP1;
    for (int i = threadIdx.x; i < CHUNK; i += TPB) h[i] = 0;
    __syncthreads();
    int lo  = chunk * CHUNK;
    int per = ((E + GP1 - 1) / GP1 + 3) & ~3;
    int e0  = p * per;
    int e1  = e0 + per; if (e1 > E) e1 = E;
    if (e0 < e1) {
        int nvec = (e1 - e0) >> 2;
        const int4* vsrc = (const int4*)(arr + e0);
        for (int i = threadIdx.x; i < nvec; i += TPB) {
            int4 v = vsrc[i];
            unsigned d;
            d = (unsigned)(v.x - lo); if (d < CHUNK) atomicAdd(&h[d], 1);
            d = (unsigned)(v.y - lo); if (d < CHUNK) atomicAdd(&h[d], 1);
            d = (unsigned)(v.z - lo); if (d < CHUNK) atomicAdd(&h[d], 1);
            d = (unsigned)(v.w - lo); if (d < CHUNK) atomicAdd(&h[d], 1);
        }
        for (int e = e0 + (nvec << 2) + threadIdx.x; e < e1; e += TPB) {
            unsigned d = (unsigned)(arr[e] - lo);
            if (d < CHUNK) atomicAdd(&h[d], 1);
        }
    }
    __syncthreads();
    int* dstp = part + (size_t)b * CHUNK;
    for (int i = threadIdx.x; i < CHUNK; i += TPB) dstp[i] = h[i];
}

// ---------------- counts -> per-partition exclusive offsets (in place); din for free ---
__global__ void offset_kernel(int* __restrict__ part, int* __restrict__ din, int N) {
    int n = blockIdx.x * TPB + threadIdx.x;
    if (n >= N) return;
    int c = n / CHUNK, o = n % CHUNK;
    int* base = part + ((size_t)c * GP1) * CHUNK + o;
    int run = n * CAP;
    #pragma unroll
    for (int p = 0; p < GP1; p++) {
        int t = base[(size_t)p * CHUNK];
        base[(size_t)p * CHUNK] = run;
        run += t;
    }
    din[n] = run - n * CAP;
}

// ---------------- scatter via LDS cursors: NO global atomics ----------------
__global__ void scatterC_kernel(const int* __restrict__ src, const int* __restrict__ dst,
                                const int* __restrict__ part, int* __restrict__ esrc, int E) {
    __shared__ int cur[CHUNK];
    int b     = blockIdx.x;
    int chunk = b / GP1;
    int p     = b % GP1;
    const int* offp = part + (size_t)b * CHUNK;
    for (int i = threadIdx.x; i < CHUNK; i += TPB) cur[i] = offp[i];
    __syncthreads();
    int lo  = chunk * CHUNK;
    int per = ((E + GP1 - 1) / GP1 + 3) & ~3;
    int e0  = p * per;
    int e1  = e0 + per; if (e1 > E) e1 = E;
    if (e0 < e1) {
        int nvec = (e1 - e0) >> 2;
        const int4* d4 = (const int4*)(dst + e0);
        const int4* s4 = (const int4*)(src + e0);
        for (int i = threadIdx.x; i < nvec; i += TPB) {
            int4 d = d4[i];
            int4 s = s4[i];
            unsigned u; int pos;
            u = (unsigned)(d.x - lo);
            if (u < CHUNK) { pos = atomicAdd(&cur[u], 1); if (pos < (lo + (int)u + 1) * CAP) esrc[pos] = s.x; }
            u = (unsigned)(d.y - lo);
            if (u < CHUNK) { pos = atomicAdd(&cur[u], 1); if (pos < (lo + (int)u + 1) * CAP) esrc[pos] = s.y; }
            u = (unsigned)(d.z - lo);
            if (u < CHUNK) { pos = atomicAdd(&cur[u], 1); if (pos < (lo + (int)u + 1) * CAP) esrc[pos] = s.z; }
            u = (unsigned)(d.w - lo);
            if (u < CHUNK) { pos = atomicAdd(&cur[u], 1); if (pos < (lo + (int)u + 1) * CAP) esrc[pos] = s.w; }
        }
        for (int e = e0 + (nvec << 2) + threadIdx.x; e < e1; e += TPB) {
            int dd = dst[e];
            unsigned u = (unsigned)(dd - lo);
            if (u < CHUNK) { int pos = atomicAdd(&cur[u], 1); if (pos < (dd + 1) * CAP) esrc[pos] = src[e]; }
        }
    }
}

// ---------------- GEMM 1: [N,128] @ [128,64]; epilogue -> two sout-scaled bf16 copies ---
__global__ void gemm1_kernel(const float* __restrict__ x, const float* __restrict__ W,
                             const int* __restrict__ dout1, const int* __restrict__ dout2,
                             unsigned short* __restrict__ Y0, unsigned short* __restrict__ Y1,
                             int N) {
    __shared__ float xs[64 * 128];   // 32 KB
    __shared__ float ws[128 * 64];   // 32 KB
    int tid  = threadIdx.x;
    int row0 = blockIdx.x * 64;
    for (int i = tid; i < 2048; i += TPB)
        ((float4*)ws)[i] = ((const float4*)W)[i];
    for (int i = tid; i < 2048; i += TPB) {
        int r = row0 + (i >> 5);
        ((float4*)xs)[i] = (r < N) ? ((const float4*)x)[(size_t)r * 32 + (i & 31)]
                                   : make_float4(0.f, 0.f, 0.f, 0.f);
    }
    __syncthreads();
    int tr = tid >> 4, tc = tid & 15;
    float acc[4][4] = {};
    for (int k4 = 0; k4 < 32; k4++) {
        float4 a[4], b[4];
        #pragma unroll
        for (int j = 0; j < 4; j++) a[j] = ((float4*)xs)[(tr * 4 + j) * 32 + k4];
        #pragma unroll
        for (int j = 0; j < 4; j++) b[j] = ((float4*)ws)[(k4 * 4 + j) * 16 + tc];
        #pragma unroll
        for (int i = 0; i < 4; i++) {
            float4 ai = a[i];
            acc[i][0] += ai.x * b[0].x + ai.y * b[1].x + ai.z * b[2].x + ai.w * b[3].x;
            acc[i][1] += ai.x * b[0].y + ai.y * b[1].y + ai.z * b[2].y + ai.w * b[3].y;
            acc[i][2] += ai.x * b[0].z + ai.y * b[1].z + ai.z * b[2].z + ai.w * b[3].z;
            acc[i][3] += ai.x * b[0].w + ai.y * b[1].w + ai.z * b[2].w + ai.w * b[3].w;
        }
    }
    #pragma unroll
    for (int i = 0; i < 4; i++) {
        int r = row0 + tr * 4 + i;
        if (r < N) {
            int g0 = dout1[r], g1 = dout2[r];
            float s0 = rsqrtf((float)(g0 > 1 ? g0 : 1));
            float s1 = rsqrtf((float)(g1 > 1 ? g1 : 1));
            size_t o = (size_t)r * 64 + tc * 4;
            ushort4 p0 = make_ushort4(f2bf(acc[i][0] * s0), f2bf(acc[i][1] * s0),
                                      f2bf(acc[i][2] * s0), f2bf(acc[i][3] * s0));
            ushort4 p1 = make_ushort4(f2bf(acc[i][0] * s1), f2bf(acc[i][1] * s1),
                                      f2bf(acc[i][2] * s1), f2bf(acc[i][3] * s1));
            *(ushort4*)(Y0 + o) = p0;
            *(ushort4*)(Y1 + o) = p1;
        }
    }
}

// ---------------- FUSED layer-1 gather + bias/relu + @W2 + sout scale -> bf16 H2 -------
// one wave per node; lane (l=lane&31) owns feature PAIR (2l,2l+1); half-waves split edges.
// Epilogue: W2 half-column cached in registers; h row via broadcast float4 LDS reads.
__global__ void agg1f_kernel(const int* __restrict__ esrc, const int* __restrict__ din,
                             const unsigned short* __restrict__ Yg,
                             const float* __restrict__ b1, const float* __restrict__ W2,
                             const int* __restrict__ doutg,
                             unsigned short* __restrict__ H2, int N) {
    __shared__ float hs[4][64];      // per-wave h row
    int tid  = threadIdx.x;
    int w    = tid >> 6;
    int lane = tid & 63;
    int half = lane >> 5;
    int l    = lane & 31;

    // cache this lane's W2 half-column: W2[(half*32+k)*32 + l], k = 0..31 (L2-hot)
    float4 w2r[8];
    #pragma unroll
    for (int k4 = 0; k4 < 8; k4++) {
        int k = (half << 5) + (k4 << 2);
        w2r[k4].x = W2[(k + 0) * 32 + l];
        w2r[k4].y = W2[(k + 1) * 32 + l];
        w2r[k4].z = W2[(k + 2) * 32 + l];
        w2r[k4].w = W2[(k + 3) * 32 + l];
    }

    int node = blockIdx.x * 4 + w;
    if (node >= N) return;

    int dn = din[node];
    float si = rsqrtf((float)(dn > 1 ? dn : 1));
    if (dn > CAP) dn = CAP;
    const int* es = esrc + (size_t)node * CAP;

    float a0 = 0.f, a1 = 0.f;
    int i = 0;
    for (; i + 8 <= dn; i += 8) {
        int4 a = *(const int4*)(es + i);
        int4 b = *(const int4*)(es + i + 4);
        int s0 = half ? a.y : a.x;
        int s1 = half ? a.w : a.z;
        int s2 = half ? b.y : b.x;
        int s3 = half ? b.w : b.z;
        unsigned v0 = *(const unsigned*)(Yg + (size_t)s0 * 64 + 2 * l);
        unsigned v1 = *(const unsigned*)(Yg + (size_t)s1 * 64 + 2 * l);
        unsigned v2 = *(const unsigned*)(Yg + (size_t)s2 * 64 + 2 * l);
        unsigned v3 = *(const unsigned*)(Yg + (size_t)s3 * 64 + 2 * l);
        a0 += bflo(v0) + bflo(v1) + bflo(v2) + bflo(v3);
        a1 += bfhi(v0) + bfhi(v1) + bfhi(v2) + bfhi(v3);
    }
    for (int e = i + half; e < dn; e += 2) {
        unsigned v = *(const unsigned*)(Yg + (size_t)es[e] * 64 + 2 * l);
        a0 += bflo(v);
        a1 += bfhi(v);
    }
    a0 += __shfl_xor(a0, 32);
    a1 += __shfl_xor(a1, 32);

    if (half == 0) {
        float2 bb = *(const float2*)(b1 + 2 * l);
        float h0 = a0 * si + bb.x; h0 = h0 > 0.f ? h0 : 0.f;
        float h1 = a1 * si + bb.y; h1 = h1 > 0.f ? h1 : 0.f;
        *(float2*)&hs[w][2 * l] = make_float2(h0, h1);
    }
    // wave-internal LDS write->read; compiler waitcnt orders it, no barrier needed.

    const float4* hrow = (const float4*)(hs[w] + (half << 5));
    float part = 0.f;
    #pragma unroll
    for (int k4 = 0; k4 < 8; k4++) {
        float4 hv = hrow[k4];            // broadcast read (<=2 addrs per wave: free)
        part += hv.x * w2r[k4].x + hv.y * w2r[k4].y + hv.z * w2r[k4].z + hv.w * w2r[k4].w;
    }
    float total = part + __shfl_xor(part, 32);
    if (half == 0) {
        int g = doutg[node];
        float so = rsqrtf((float)(g > 1 ? g : 1));
        H2[(size_t)node * 32 + l] = f2bf(total * so);
    }
}

// ---------------- layer-2 gather (packed bf16 pairs) + mean epilogue ----------------
// 16-lane group per node (4 nodes/wave); lane owns feature pair (2l,2l+1).
__global__ void agg2_kernel(const int* __restrict__ esrc, const int* __restrict__ din,
                            const unsigned short* __restrict__ H2,
                            const float* __restrict__ b2, float* __restrict__ out,
                            int N, int first) {
    int node = blockIdx.x * 16 + (threadIdx.x >> 4);
    int l    = threadIdx.x & 15;
    if (node >= N) return;
    int dn = din[node];
    float si = rsqrtf((float)(dn > 1 ? dn : 1));
    if (dn > CAP) dn = CAP;
    const int* es = esrc + (size_t)node * CAP;
    float a0 = 0.f, a1 = 0.f;
    int i = 0;
    for (; i + 8 <= dn; i += 8) {
        int4 a = *(const int4*)(es + i);
        int4 b = *(const int4*)(es + i + 4);
        unsigned v0 = *(const unsigned*)(H2 + (size_t)a.x * 32 + 2 * l);
        unsigned v1 = *(const unsigned*)(H2 + (size_t)a.y * 32 + 2 * l);
        unsigned v2 = *(const unsigned*)(H2 + (size_t)a.z * 32 + 2 * l);
        unsigned v3 = *(const unsigned*)(H2 + (size_t)a.w * 32 + 2 * l);
        unsigned v4 = *(const unsigned*)(H2 + (size_t)b.x * 32 + 2 * l);
        unsigned v5 = *(const unsigned*)(H2 + (size_t)b.y * 32 + 2 * l);
        unsigned v6 = *(const unsigned*)(H2 + (size_t)b.z * 32 + 2 * l);
        unsigned v7 = *(const unsigned*)(H2 + (size_t)b.w * 32 + 2 * l);
        a0 += bflo(v0) + bflo(v1) + bflo(v2) + bflo(v3)
            + bflo(v4) + bflo(v5) + bflo(v6) + bflo(v7);
        a1 += bfhi(v0) + bfhi(v1) + bfhi(v2) + bfhi(v3)
            + bfhi(v4) + bfhi(v5) + bfhi(v6) + bfhi(v7);
    }
    if (i + 4 <= dn) {
        int4 a = *(const int4*)(es + i);
        unsigned v0 = *(const unsigned*)(H2 + (size_t)a.x * 32 + 2 * l);
        unsigned v1 = *(const unsigned*)(H2 + (size_t)a.y * 32 + 2 * l);
        unsigned v2 = *(const unsigned*)(H2 + (size_t)a.z * 32 + 2 * l);
        unsigned v3 = *(const unsigned*)(H2 + (size_t)a.w * 32 + 2 * l);
        a0 += bflo(v0) + bflo(v1) + bflo(v2) + bflo(v3);
        a1 += bfhi(v0) + bfhi(v1) + bfhi(v2) + bfhi(v3);
        i += 4;
    }
    for (; i < dn; i++) {
        unsigned v = *(const unsigned*)(H2 + (size_t)es[i] * 32 + 2 * l);
        a0 += bflo(v);
        a1 += bfhi(v);
    }
    float2 bb = *(const float2*)(b2 + 2 * l);
    float v0 = 0.5f * (a0 * si + bb.x);
    float v1 = 0.5f * (a1 * si + bb.y);
    size_t o = (size_t)node * 32 + 2 * l;
    if (first) {
        *(float2*)(out + o) = make_float2(v0, v1);
    } else {
        float2 prev = *(const float2*)(out + o);
        *(float2*)(out + o) = make_float2(prev.x + v0, prev.y + v1);
    }
}

extern "C" void kernel_launch(void* const* d_in, const int* in_sizes, int n_in,
                              void* d_out, int out_size, void* d_ws, size_t ws_size,
                              hipStream_t stream) {
    const float* x    = (const float*)d_in[0];
    const int* srcs[2] = {(const int*)d_in[1], (const int*)d_in[3]};
    const int* dsts[2] = {(const int*)d_in[2], (const int*)d_in[4]};
    const float* W1   = (const float*)d_in[5];
    const float* b1   = (const float*)d_in[6];
    const float* W2   = (const float*)d_in[7];
    const float* b2   = (const float*)d_in[8];
    float* out        = (float*)d_out;

    const int N = in_sizes[0] / 128;   // 100000
    const int E = in_sizes[1];         // 1600000
    const int nchunk = (N + CHUNK - 1) / CHUNK;   // 7

    // byte layout (78.4 MB dedicated):
    //   Y1G0 (bf16 64N) 12.8M | Y1G1 12.8M | SCR 25.6M | H2 (bf16 32N) 6.4M
    //   | DOUT (2N int) 0.8M | DIN (2N int) 0.8M | ESRC (CAP*N int) 19.2M
    // Aliases (recomputed, CHUNK=16384, nchunk=7):
    //   PART2 = 2*7*GP2*CHUNK*4B = 29.36 MB over [Y1G0|Y1G1|SCR head] (51.2 MB window;
    //     consumed by histreduce before gemm1 writes Y1G0/Y1G1).
    //   PART1 = 7*GP1*CHUNK*4B = 29.36 MB over [SCR|H2] (32.0 MB window; consumed by
    //     scatterC before agg1f writes H2).
    unsigned short* Y1G0 = (unsigned short*)d_ws;
    unsigned short* Y1G1 = Y1G0 + (size_t)64 * N;
    float* SCR           = (float*)(Y1G1 + (size_t)64 * N);
    unsigned short* H2   = (unsigned short*)(SCR + (size_t)64 * N);
    int* DOUT            = (int*)(H2 + (size_t)32 * N);
    int* DIN             = DOUT + (size_t)2 * N;
    int* ESRC            = DIN + (size_t)2 * N;
    int* PART2           = (int*)d_ws;
    int* PART1           = (int*)SCR;

    // out-degrees for both graphs (no global atomics)
    hist_kernel<<<2 * nchunk * GP2, TPB, 0, stream>>>(srcs[0], srcs[1], PART2, E, nchunk);
    histreduce_kernel<<<(2 * N + TPB - 1) / TPB, TPB, 0, stream>>>(PART2, DOUT, N, nchunk);

    gemm1_kernel<<<(N + 63) / 64, TPB, 0, stream>>>(x, W1, DOUT, DOUT + N, Y1G0, Y1G1, N);

    for (int g = 0; g < 2; g++) {
        const unsigned short* Yg = g == 0 ? Y1G0 : Y1G1;
        int* din = DIN + (size_t)g * N;

        // slack-bucket CSR without any global atomics
        hist1_kernel<<<nchunk * GP1, TPB, 0, stream>>>(dsts[g], PART1, E);
        offset_kernel<<<(N + TPB - 1) / TPB, TPB, 0, stream>>>(PART1, din, N);
        scatterC_kernel<<<nchunk * GP1, TPB, 0, stream>>>(srcs[g], dsts[g], PART1, ESRC, E);

        agg1f_kernel<<<(N + 3) / 4, TPB, 0, stream>>>(ESRC, din, Yg, b1, W2,
                                                      DOUT + (size_t)g * N, H2, N);
        agg2_kernel<<<(N + 15) / 16, TPB, 0, stream>>>(ESRC, din, H2, b2, out, N, g == 0);
    }
}